// Round 1
// baseline (3487.621 us; speedup 1.0000x reference)
//
#include <hip/hip_runtime.h>
#include <math.h>

// Problem constants
#define B_  32
#define L_  1024
#define T_  (B_ * L_)       // 32768 tokens
#define DM_ 128
#define DI_ 256
#define DS_ 16
#define DC_ 4
#define DR_ 8
#define NC_ 10

__device__ __forceinline__ float sigmoidf_(float x) { return 1.0f / (1.0f + __expf(-x)); }
__device__ __forceinline__ float siluf_(float x)    { return x * sigmoidf_(x); }
__device__ __forceinline__ float softplusf_(float x) {
    return (x > 15.0f) ? x : __logf(1.0f + __expf(x));
}

// ---------------- embed: h[t][m] = sum_c x[b,c,l]*Win[c][m] + bin[m] -------------
__global__ __launch_bounds__(128) void k_embed(const float* __restrict__ x,
        const float* __restrict__ Win, const float* __restrict__ bin,
        float* __restrict__ h) {
    int t = blockIdx.x;               // 0..32767
    int b = t >> 10, l = t & 1023;
    int m = threadIdx.x;
    const float* xb = x + (size_t)b * 3 * 1024 + l;
    float acc = bin[m];
    acc = fmaf(xb[0],    Win[m],        acc);
    acc = fmaf(xb[1024], Win[128 + m],  acc);
    acc = fmaf(xb[2048], Win[256 + m],  acc);
    h[(size_t)t * 128 + m] = acc;
}

// ---------------- layernorm over DM=128, one wave per token ----------------------
__global__ __launch_bounds__(256) void k_ln(const float* __restrict__ h,
        const float* __restrict__ w, const float* __restrict__ b,
        float* __restrict__ z) {
    int wid = threadIdx.x >> 6, lane = threadIdx.x & 63;
    int t = blockIdx.x * 4 + wid;
    const float* hr = h + (size_t)t * 128;
    float2 v = *(const float2*)(hr + lane * 2);
    float s = v.x + v.y, sq = v.x * v.x + v.y * v.y;
#pragma unroll
    for (int off = 1; off < 64; off <<= 1) {
        s += __shfl_xor(s, off);
        sq += __shfl_xor(sq, off);
    }
    float mean = s * (1.0f / 128.0f);
    float var = sq * (1.0f / 128.0f) - mean * mean;
    float rstd = rsqrtf(var + 1e-5f);
    float2 wv = *(const float2*)(w + lane * 2);
    float2 bv = *(const float2*)(b + lane * 2);
    float2 o;
    o.x = (v.x - mean) * rstd * wv.x + bv.x;
    o.y = (v.y - mean) * rstd * wv.y + bv.y;
    *(float2*)(z + (size_t)t * 128 + lane * 2) = o;
}

// ---------------- fp32 tiled GEMM: C[M][N] (+=) A[M][K] @ W[K][N] (+bias) --------
// 64x64 tile, 256 threads, 4x4 accum per thread. M,N,K all multiples of 64.
template<int K, int N, bool RESID>
__global__ __launch_bounds__(256) void k_gemm(const float* __restrict__ A,
        const float* __restrict__ W, const float* __restrict__ bias,
        float* __restrict__ C) {
    __shared__ float As[64][68];   // As[k][m]
    __shared__ float Bs[64][68];   // Bs[k][n]
    int tid = threadIdx.x;
    int tx = tid & 15, ty = tid >> 4;
    int bm = blockIdx.x, bn = blockIdx.y;
    const float* Ab = A + (size_t)bm * 64 * K;
    const float* Wb = W + bn * 64;
    float acc[4][4] = {};
    for (int k0 = 0; k0 < K; k0 += 64) {
#pragma unroll
        for (int r = 0; r < 4; ++r) {
            int idx = tid + 256 * r;          // 0..1023
            int m = idx >> 4, kq = idx & 15;
            float4 v = *(const float4*)(Ab + (size_t)m * K + k0 + kq * 4);
            As[kq * 4 + 0][m] = v.x;
            As[kq * 4 + 1][m] = v.y;
            As[kq * 4 + 2][m] = v.z;
            As[kq * 4 + 3][m] = v.w;
        }
#pragma unroll
        for (int r = 0; r < 4; ++r) {
            int idx = tid + 256 * r;
            int k = idx >> 4, nq = idx & 15;
            *(float4*)(&Bs[k][nq * 4]) = *(const float4*)(Wb + (size_t)(k0 + k) * N + nq * 4);
        }
        __syncthreads();
#pragma unroll
        for (int k = 0; k < 64; ++k) {
            float4 a = *(const float4*)(&As[k][ty * 4]);
            float4 bv = *(const float4*)(&Bs[k][tx * 4]);
            float av[4] = {a.x, a.y, a.z, a.w};
            float bb[4] = {bv.x, bv.y, bv.z, bv.w};
#pragma unroll
            for (int i = 0; i < 4; ++i)
#pragma unroll
                for (int j = 0; j < 4; ++j)
                    acc[i][j] = fmaf(av[i], bb[j], acc[i][j]);
        }
        __syncthreads();
    }
    float* Cb = C + (size_t)(bm * 64) * N + bn * 64;
#pragma unroll
    for (int i = 0; i < 4; ++i) {
        int row = ty * 4 + i;
        float4 o;
        o.x = acc[i][0]; o.y = acc[i][1]; o.z = acc[i][2]; o.w = acc[i][3];
        float* cp = Cb + (size_t)row * N + tx * 4;
        if (RESID) {
            float4 c = *(const float4*)cp;
            float4 b4 = *(const float4*)(bias + bn * 64 + tx * 4);
            o.x += c.x + b4.x; o.y += c.y + b4.y;
            o.z += c.z + b4.z; o.w += c.w + b4.w;
        }
        *(float4*)cp = o;
    }
}

// ---------------- causal depthwise conv (width 4) + SiLU -------------------------
// xin is the first DI_ columns of xz (stride 512).
__global__ __launch_bounds__(256) void k_conv(const float* __restrict__ xz,
        const float* __restrict__ cw, const float* __restrict__ cb,
        float* __restrict__ xc) {
    int t = blockIdx.x, d = threadIdx.x;
    int l = t & 1023;
    float w0 = cw[d * 4 + 0], w1 = cw[d * 4 + 1], w2 = cw[d * 4 + 2], w3 = cw[d * 4 + 3];
    const float* xp = xz + (size_t)t * 512 + d;
    float acc = cb[d];
    if (l >= 3) acc = fmaf(xp[-3 * 512], w0, acc);
    if (l >= 2) acc = fmaf(xp[-2 * 512], w1, acc);
    if (l >= 1) acc = fmaf(xp[-1 * 512], w2, acc);
    acc = fmaf(xp[0], w3, acc);
    xc[(size_t)t * 256 + d] = siluf_(acc);
}

// ---------------- x_proj: proj[T][40] = xc[T][256] @ xpw[256][40] ----------------
// block = 16 tokens, 256 threads
__global__ __launch_bounds__(256) void k_xproj(const float* __restrict__ xc,
        const float* __restrict__ xpw, float* __restrict__ proj) {
    __shared__ float xcs[16][257];
    int tid = threadIdx.x;
    int t0 = blockIdx.x * 16;
#pragma unroll
    for (int r = 0; r < 16; ++r) {
        int idx = r * 256 + tid;
        xcs[idx >> 8][idx & 255] = xc[(size_t)t0 * 256 + idx];
    }
    __syncthreads();
#pragma unroll
    for (int jj = 0; jj < 3; ++jj) {
        int j = jj * 256 + tid;
        if (j < 640) {
            int to = j & 15, c = j >> 4;
            float acc = 0.0f;
#pragma unroll 8
            for (int k = 0; k < 256; ++k) acc = fmaf(xcs[to][k], xpw[k * 40 + c], acc);
            proj[(size_t)(t0 + to) * 40 + c] = acc;
        }
    }
}

// ---------------- SSM scan, fused delta + D-skip + alpha-blend + gate ------------
// grid (4, 32): blockIdx.x = d-group (64 d's), blockIdx.y = b.
// 256 threads: 4 lanes per d, each lane handles 4 of the 16 states.
__global__ __launch_bounds__(256) void k_scan(
        const float* __restrict__ proj, const float* __restrict__ xc,
        const float* __restrict__ xz /* gate at +256 */,
        const float* __restrict__ dtw, const float* __restrict__ dtb,
        const float* __restrict__ Alog, const float* __restrict__ Dp,
        float* __restrict__ y) {
    __shared__ float projs[64 * 40];
    int b = blockIdx.y, dg = blockIdx.x;
    int tid = threadIdx.x;
    int d = dg * 64 + (tid >> 2);
    int q = tid & 3;
    float aa[4];
    float hs[4] = {0.0f, 0.0f, 0.0f, 0.0f};
#pragma unroll
    for (int j = 0; j < 4; ++j)
        aa[j] = -__expf(Alog[d * 16 + q * 4 + j]) * 1.44269504088896f;  // A*log2(e)
    float dtwc[8];
#pragma unroll
    for (int r = 0; r < 8; ++r) dtwc[r] = dtw[r * 256 + d];
    float dtbd = dtb[d], Dpd = Dp[d];
    const float* projB = proj + (size_t)b * 1024 * 40;
    const float* xcB   = xc   + (size_t)b * 1024 * 256;
    const float* gateB = xz   + (size_t)b * 1024 * 512 + 256;
    float* yB          = y    + (size_t)b * 1024 * 256;

    for (int t0 = 0; t0 < 1024; t0 += 64) {
        __syncthreads();
#pragma unroll
        for (int r = 0; r < 10; ++r)
            projs[r * 256 + tid] = projB[(size_t)t0 * 40 + r * 256 + tid];
        __syncthreads();
        for (int tt = 0; tt < 64; ++tt) {
            const float* pr = projs + tt * 40;
            float dt = dtbd;
#pragma unroll
            for (int r = 0; r < 8; ++r) dt = fmaf(pr[r], dtwc[r], dt);
            float delta = softplusf_(dt);
            int t = t0 + tt;
            float u = xcB[(size_t)t * 256 + d];
            float du = delta * u;
            float ys = 0.0f;
#pragma unroll
            for (int j = 0; j < 4; ++j) {
                float dA = exp2f(delta * aa[j]);
                hs[j] = fmaf(dA, hs[j], du * pr[8 + q * 4 + j]);
                ys = fmaf(hs[j], pr[24 + q * 4 + j], ys);
            }
            ys += __shfl_xor(ys, 1);
            ys += __shfl_xor(ys, 2);
            if (q == 0) {
                float g = gateB[(size_t)t * 512 + d];
                float yv = ys + u * Dpd;
                yv = 0.7f * yv + 0.3f * u;       // Luenberger blend
                yv *= siluf_(g);
                yB[(size_t)t * 256 + d] = yv;
            }
        }
    }
}

// ---------------- mean-pool over L ----------------------------------------------
__global__ __launch_bounds__(128) void k_pool(const float* __restrict__ h,
        float* __restrict__ pooled) {
    int b = blockIdx.x, m = threadIdx.x;
    const float* hb = h + (size_t)b * 1024 * 128 + m;
    float acc = 0.0f;
    for (int l = 0; l < 1024; ++l) acc += hb[(size_t)l * 128];
    pooled[b * 128 + m] = acc * (1.0f / 1024.0f);
}

// ---------------- final LN + classifier -----------------------------------------
__global__ __launch_bounds__(128) void k_head(const float* __restrict__ pooled,
        const float* __restrict__ nw, const float* __restrict__ nb,
        const float* __restrict__ cw, const float* __restrict__ cb,
        float* __restrict__ out) {
    __shared__ float zs[128];
    __shared__ float red[128];
    int b = blockIdx.x, m = threadIdx.x;
    float v = pooled[b * 128 + m];
    red[m] = v;
    __syncthreads();
    for (int off = 64; off; off >>= 1) {
        if (m < off) red[m] += red[m + off];
        __syncthreads();
    }
    float mean = red[0] * (1.0f / 128.0f);
    __syncthreads();
    float dv = v - mean;
    red[m] = dv * dv;
    __syncthreads();
    for (int off = 64; off; off >>= 1) {
        if (m < off) red[m] += red[m + off];
        __syncthreads();
    }
    float rstd = rsqrtf(red[0] * (1.0f / 128.0f) + 1e-5f);
    zs[m] = dv * rstd * nw[m] + nb[m];
    __syncthreads();
    if (m < NC_) {
        float acc = cb[m];
#pragma unroll 8
        for (int k = 0; k < 128; ++k) acc = fmaf(zs[k], cw[k * 10 + m], acc);
        out[b * 10 + m] = acc;
    }
}

extern "C" void kernel_launch(void* const* d_in, const int* in_sizes, int n_in,
                              void* d_out, int out_size, void* d_ws, size_t ws_size,
                              hipStream_t stream) {
    const float* x    = (const float*)d_in[0];
    const float* Win  = (const float*)d_in[1];
    const float* bin  = (const float*)d_in[2];
    const float* lnw  = (const float*)d_in[3];
    const float* lnb  = (const float*)d_in[4];
    const float* ipw  = (const float*)d_in[5];
    const float* cw   = (const float*)d_in[6];
    const float* cb   = (const float*)d_in[7];
    const float* xpw  = (const float*)d_in[8];
    const float* dtw  = (const float*)d_in[9];
    const float* dtb  = (const float*)d_in[10];
    const float* Alog = (const float*)d_in[11];
    const float* Dp   = (const float*)d_in[12];
    const float* opw  = (const float*)d_in[13];
    const float* opb  = (const float*)d_in[14];
    const float* nw   = (const float*)d_in[15];
    const float* nb   = (const float*)d_in[16];
    const float* clw  = (const float*)d_in[17];
    const float* clb  = (const float*)d_in[18];

    float* ws     = (float*)d_ws;
    float* h      = ws;                       // T*128   = 4,194,304
    float* z      = h    + 4194304;           // T*128   = 4,194,304
    float* xz     = z    + 4194304;           // T*512   = 16,777,216
    float* xc     = xz   + 16777216;          // T*256   = 8,388,608
    float* proj   = xc   + 8388608;           // T*40    = 1,310,720
    float* y      = proj + 1310720;           // T*256   = 8,388,608
    float* pooled = y    + 8388608;           // 4096

    k_embed<<<T_, 128, 0, stream>>>(x, Win, bin, h);
    for (int lay = 0; lay < 4; ++lay) {
        k_ln<<<T_ / 4, 256, 0, stream>>>(h, lnw + lay * 128, lnb + lay * 128, z);
        k_gemm<128, 512, false><<<dim3(T_ / 64, 8), 256, 0, stream>>>(
            z, ipw + (size_t)lay * 128 * 512, nullptr, xz);
        k_conv<<<T_, 256, 0, stream>>>(xz, cw + lay * 1024, cb + lay * 256, xc);
        k_xproj<<<T_ / 16, 256, 0, stream>>>(xc, xpw + lay * 256 * 40, proj);
        k_scan<<<dim3(4, 32), 256, 0, stream>>>(proj, xc, xz,
            dtw + lay * 2048, dtb + lay * 256, Alog + lay * 4096, Dp + lay * 256, y);
        k_gemm<256, 128, true><<<dim3(T_ / 64, 2), 256, 0, stream>>>(
            y, opw + (size_t)lay * 256 * 128, opb + lay * 128, h);
    }
    k_pool<<<32, 128, 0, stream>>>(h, pooled);
    k_head<<<32, 128, 0, stream>>>(pooled, nw, nb, clw, clb, (float*)d_out);
}

// Round 2
// 1379.806 us; speedup vs baseline: 2.5276x; 2.5276x over previous
//
#include <hip/hip_runtime.h>
#include <math.h>

// Problem constants
#define B_  32
#define L_  1024
#define T_  (B_ * L_)       // 32768 tokens
#define DM_ 128
#define DI_ 256
#define DS_ 16
#define DC_ 4
#define DR_ 8
#define NC_ 10
#define CHUNK_ 64
#define NCH_  (L_ / CHUNK_)   // 16 chunks

__device__ __forceinline__ float sigmoidf_(float x) { return 1.0f / (1.0f + __expf(-x)); }
__device__ __forceinline__ float siluf_(float x)    { return x * sigmoidf_(x); }
__device__ __forceinline__ float softplusf_(float x) {
    return (x > 15.0f) ? x : __logf(1.0f + __expf(x));
}

// ---------------- embed: h[t][m] = sum_c x[b,c,l]*Win[c][m] + bin[m] -------------
__global__ __launch_bounds__(128) void k_embed(const float* __restrict__ x,
        const float* __restrict__ Win, const float* __restrict__ bin,
        float* __restrict__ h) {
    int t = blockIdx.x;               // 0..32767
    int b = t >> 10, l = t & 1023;
    int m = threadIdx.x;
    const float* xb = x + (size_t)b * 3 * 1024 + l;
    float acc = bin[m];
    acc = fmaf(xb[0],    Win[m],        acc);
    acc = fmaf(xb[1024], Win[128 + m],  acc);
    acc = fmaf(xb[2048], Win[256 + m],  acc);
    h[(size_t)t * 128 + m] = acc;
}

// ---------------- layernorm over DM=128, one wave per token ----------------------
__global__ __launch_bounds__(256) void k_ln(const float* __restrict__ h,
        const float* __restrict__ w, const float* __restrict__ b,
        float* __restrict__ z) {
    int wid = threadIdx.x >> 6, lane = threadIdx.x & 63;
    int t = blockIdx.x * 4 + wid;
    const float* hr = h + (size_t)t * 128;
    float2 v = *(const float2*)(hr + lane * 2);
    float s = v.x + v.y, sq = v.x * v.x + v.y * v.y;
#pragma unroll
    for (int off = 1; off < 64; off <<= 1) {
        s += __shfl_xor(s, off);
        sq += __shfl_xor(sq, off);
    }
    float mean = s * (1.0f / 128.0f);
    float var = sq * (1.0f / 128.0f) - mean * mean;
    float rstd = rsqrtf(var + 1e-5f);
    float2 wv = *(const float2*)(w + lane * 2);
    float2 bv = *(const float2*)(b + lane * 2);
    float2 o;
    o.x = (v.x - mean) * rstd * wv.x + bv.x;
    o.y = (v.y - mean) * rstd * wv.y + bv.y;
    *(float2*)(z + (size_t)t * 128 + lane * 2) = o;
}

// ---------------- fp32 tiled GEMM: C[M][N] (+=) A[M][K] @ W[K][N] (+bias) --------
template<int K, int N, bool RESID>
__global__ __launch_bounds__(256) void k_gemm(const float* __restrict__ A,
        const float* __restrict__ W, const float* __restrict__ bias,
        float* __restrict__ C) {
    __shared__ float As[64][68];   // As[k][m]
    __shared__ float Bs[64][68];   // Bs[k][n]
    int tid = threadIdx.x;
    int tx = tid & 15, ty = tid >> 4;
    int bm = blockIdx.x, bn = blockIdx.y;
    const float* Ab = A + (size_t)bm * 64 * K;
    const float* Wb = W + bn * 64;
    float acc[4][4] = {};
    for (int k0 = 0; k0 < K; k0 += 64) {
#pragma unroll
        for (int r = 0; r < 4; ++r) {
            int idx = tid + 256 * r;          // 0..1023
            int m = idx >> 4, kq = idx & 15;
            float4 v = *(const float4*)(Ab + (size_t)m * K + k0 + kq * 4);
            As[kq * 4 + 0][m] = v.x;
            As[kq * 4 + 1][m] = v.y;
            As[kq * 4 + 2][m] = v.z;
            As[kq * 4 + 3][m] = v.w;
        }
#pragma unroll
        for (int r = 0; r < 4; ++r) {
            int idx = tid + 256 * r;
            int k = idx >> 4, nq = idx & 15;
            *(float4*)(&Bs[k][nq * 4]) = *(const float4*)(Wb + (size_t)(k0 + k) * N + nq * 4);
        }
        __syncthreads();
#pragma unroll
        for (int k = 0; k < 64; ++k) {
            float4 a = *(const float4*)(&As[k][ty * 4]);
            float4 bv = *(const float4*)(&Bs[k][tx * 4]);
            float av[4] = {a.x, a.y, a.z, a.w};
            float bb[4] = {bv.x, bv.y, bv.z, bv.w};
#pragma unroll
            for (int i = 0; i < 4; ++i)
#pragma unroll
                for (int j = 0; j < 4; ++j)
                    acc[i][j] = fmaf(av[i], bb[j], acc[i][j]);
        }
        __syncthreads();
    }
    float* Cb = C + (size_t)(bm * 64) * N + bn * 64;
#pragma unroll
    for (int i = 0; i < 4; ++i) {
        int row = ty * 4 + i;
        float4 o;
        o.x = acc[i][0]; o.y = acc[i][1]; o.z = acc[i][2]; o.w = acc[i][3];
        float* cp = Cb + (size_t)row * N + tx * 4;
        if (RESID) {
            float4 c = *(const float4*)cp;
            float4 b4 = *(const float4*)(bias + bn * 64 + tx * 4);
            o.x += c.x + b4.x; o.y += c.y + b4.y;
            o.z += c.z + b4.z; o.w += c.w + b4.w;
        }
        *(float4*)cp = o;
    }
}

// ---------------- causal depthwise conv (width 4) + SiLU -------------------------
__global__ __launch_bounds__(256) void k_conv(const float* __restrict__ xz,
        const float* __restrict__ cw, const float* __restrict__ cb,
        float* __restrict__ xc) {
    int t = blockIdx.x, d = threadIdx.x;
    int l = t & 1023;
    float w0 = cw[d * 4 + 0], w1 = cw[d * 4 + 1], w2 = cw[d * 4 + 2], w3 = cw[d * 4 + 3];
    const float* xp = xz + (size_t)t * 512 + d;
    float acc = cb[d];
    if (l >= 3) acc = fmaf(xp[-3 * 512], w0, acc);
    if (l >= 2) acc = fmaf(xp[-2 * 512], w1, acc);
    if (l >= 1) acc = fmaf(xp[-1 * 512], w2, acc);
    acc = fmaf(xp[0], w3, acc);
    xc[(size_t)t * 256 + d] = siluf_(acc);
}

// ---------------- x_proj: proj[T][40] = xc[T][256] @ xpw[256][40] ----------------
__global__ __launch_bounds__(256) void k_xproj(const float* __restrict__ xc,
        const float* __restrict__ xpw, float* __restrict__ proj) {
    __shared__ float xcs[16][257];
    int tid = threadIdx.x;
    int t0 = blockIdx.x * 16;
#pragma unroll
    for (int r = 0; r < 16; ++r) {
        int idx = r * 256 + tid;
        xcs[idx >> 8][idx & 255] = xc[(size_t)t0 * 256 + idx];
    }
    __syncthreads();
#pragma unroll
    for (int jj = 0; jj < 3; ++jj) {
        int j = jj * 256 + tid;
        if (j < 640) {
            int to = j & 15, c = j >> 4;
            float acc = 0.0f;
#pragma unroll 8
            for (int k = 0; k < 256; ++k) acc = fmaf(xcs[to][k], xpw[k * 40 + c], acc);
            proj[(size_t)(t0 + to) * 40 + c] = acc;
        }
    }
}

// ---------------- chunk-parallel SSM scan ----------------------------------------
// Linear recurrence h_t = dA_t * h_{t-1} + b_t split into NCH_ chunks of CHUNK_.
// Phase A (FINAL=false): local scan from h=0 -> emit P (decay product) and S
//   (local final state) per (b, chunk, d, s).
// Phase B: sequential combine over chunks -> chunk-start states H (in place of P).
// Phase C (FINAL=true): local scan from H with full fused epilogue.
// grid (4 dgroups, NCH_ chunks, B): 256 threads = 64 d x 4 q-lanes (4 states each).
template<bool FINAL>
__global__ __launch_bounds__(256) void k_scan_chunk(
        const float* __restrict__ proj, const float* __restrict__ xc,
        const float* __restrict__ xz /* gate at +256 */,
        const float* __restrict__ dtw, const float* __restrict__ dtb,
        const float* __restrict__ Alog, const float* __restrict__ Dp,
        float* __restrict__ P, float* __restrict__ S,
        float* __restrict__ y) {
    __shared__ float projs[CHUNK_ * 40];      // 10 KiB
    __shared__ float xcs[CHUNK_][64];         // 16 KiB
    __shared__ float gates[FINAL ? CHUNK_ * 64 : 1];
    int b = blockIdx.z, c = blockIdx.y, dg = blockIdx.x;
    int tid = threadIdx.x;
    int dl = tid >> 2;                        // 0..63 local d
    int d = dg * 64 + dl;
    int q = tid & 3;

    const float* projC = proj + ((size_t)b * 1024 + c * CHUNK_) * 40;
    const float* xcC   = xc   + ((size_t)b * 1024 + c * CHUNK_) * 256 + dg * 64;
    const float* gateC = xz   + ((size_t)b * 1024 + c * CHUNK_) * 512 + 256 + dg * 64;

    // ---- stage chunk operands into LDS ----
#pragma unroll
    for (int r = 0; r < (CHUNK_ * 40) / 256; ++r)
        projs[r * 256 + tid] = projC[r * 256 + tid];
#pragma unroll
    for (int r = 0; r < (CHUNK_ * 64) / 256; ++r) {
        int i = r * 256 + tid;
        xcs[i >> 6][i & 63] = xcC[(size_t)(i >> 6) * 256 + (i & 63)];
        if (FINAL)
            gates[i] = gateC[(size_t)(i >> 6) * 512 + (i & 63)];
    }

    // ---- per-thread constants ----
    float aa[4];
#pragma unroll
    for (int j = 0; j < 4; ++j)
        aa[j] = -__expf(Alog[d * 16 + q * 4 + j]) * 1.44269504088896f;  // A*log2(e)
    float dtwc[8];
#pragma unroll
    for (int r = 0; r < 8; ++r) dtwc[r] = dtw[r * 256 + d];
    float dtbd = dtb[d], Dpd = Dp[d];

    size_t psIdx = ((size_t)(b * NCH_ + c)) * 4096 + d * 16 + q * 4;
    float hs[4] = {0.0f, 0.0f, 0.0f, 0.0f};
    if (FINAL) {
        float4 h0 = *(const float4*)(P + psIdx);   // P now holds chunk-start H
        hs[0] = h0.x; hs[1] = h0.y; hs[2] = h0.z; hs[3] = h0.w;
    }
    float cumd = 0.0f;

    float* yC = y + ((size_t)b * 1024 + c * CHUNK_) * 256 + dg * 64;

    __syncthreads();
    for (int tt = 0; tt < CHUNK_; ++tt) {
        const float* pr = projs + tt * 40;
        float dt = dtbd;
#pragma unroll
        for (int r = 0; r < 8; ++r) dt = fmaf(pr[r], dtwc[r], dt);
        float delta = softplusf_(dt);
        float u = xcs[tt][dl];
        float du = delta * u;
        if (!FINAL) cumd += delta;
        float ys = 0.0f;
#pragma unroll
        for (int j = 0; j < 4; ++j) {
            float dA = exp2f(delta * aa[j]);
            hs[j] = fmaf(dA, hs[j], du * pr[8 + q * 4 + j]);
            if (FINAL) ys = fmaf(hs[j], pr[24 + q * 4 + j], ys);
        }
        if (FINAL) {
            ys += __shfl_xor(ys, 1);
            ys += __shfl_xor(ys, 2);
            if (q == 0) {
                float g = gates[tt * 64 + dl];
                float yv = ys + u * Dpd;
                yv = 0.7f * yv + 0.3f * u;        // Luenberger blend
                yv *= siluf_(g);
                yC[(size_t)tt * 256 + dl] = yv;
            }
        }
    }
    if (!FINAL) {
        float4 pv, sv;
        pv.x = exp2f(aa[0] * cumd); pv.y = exp2f(aa[1] * cumd);
        pv.z = exp2f(aa[2] * cumd); pv.w = exp2f(aa[3] * cumd);
        sv.x = hs[0]; sv.y = hs[1]; sv.z = hs[2]; sv.w = hs[3];
        *(float4*)(P + psIdx) = pv;
        *(float4*)(S + psIdx) = sv;
    }
}

// ---------------- combine chunk aggregates: H_{c+1} = P_c*H_c + S_c --------------
// One thread per (b,d,s) = 131072 threads. Overwrites P[c] with H_c in place.
__global__ __launch_bounds__(256) void k_scan_combine(float* __restrict__ P,
        const float* __restrict__ S) {
    int idx = blockIdx.x * 256 + threadIdx.x;   // b*4096 + d*16 + s
    int b = idx >> 12, rem = idx & 4095;
    float h = 0.0f;
#pragma unroll
    for (int c = 0; c < NCH_; ++c) {
        size_t base = ((size_t)(b * NCH_ + c)) * 4096 + rem;
        float p = P[base];
        float s = S[base];
        P[base] = h;                  // chunk-start state for chunk c
        h = fmaf(p, h, s);
    }
}

// ---------------- mean-pool over L ----------------------------------------------
__global__ __launch_bounds__(128) void k_pool(const float* __restrict__ h,
        float* __restrict__ pooled) {
    int b = blockIdx.x, m = threadIdx.x;
    const float* hb = h + (size_t)b * 1024 * 128 + m;
    float acc = 0.0f;
    for (int l = 0; l < 1024; ++l) acc += hb[(size_t)l * 128];
    pooled[b * 128 + m] = acc * (1.0f / 1024.0f);
}

// ---------------- final LN + classifier -----------------------------------------
__global__ __launch_bounds__(128) void k_head(const float* __restrict__ pooled,
        const float* __restrict__ nw, const float* __restrict__ nb,
        const float* __restrict__ cw, const float* __restrict__ cb,
        float* __restrict__ out) {
    __shared__ float zs[128];
    __shared__ float red[128];
    int b = blockIdx.x, m = threadIdx.x;
    float v = pooled[b * 128 + m];
    red[m] = v;
    __syncthreads();
    for (int off = 64; off; off >>= 1) {
        if (m < off) red[m] += red[m + off];
        __syncthreads();
    }
    float mean = red[0] * (1.0f / 128.0f);
    __syncthreads();
    float dv = v - mean;
    red[m] = dv * dv;
    __syncthreads();
    for (int off = 64; off; off >>= 1) {
        if (m < off) red[m] += red[m + off];
        __syncthreads();
    }
    float rstd = rsqrtf(red[0] * (1.0f / 128.0f) + 1e-5f);
    zs[m] = dv * rstd * nw[m] + nb[m];
    __syncthreads();
    if (m < NC_) {
        float acc = cb[m];
#pragma unroll 8
        for (int k = 0; k < 128; ++k) acc = fmaf(zs[k], cw[k * 10 + m], acc);
        out[b * 10 + m] = acc;
    }
}

extern "C" void kernel_launch(void* const* d_in, const int* in_sizes, int n_in,
                              void* d_out, int out_size, void* d_ws, size_t ws_size,
                              hipStream_t stream) {
    const float* x    = (const float*)d_in[0];
    const float* Win  = (const float*)d_in[1];
    const float* bin  = (const float*)d_in[2];
    const float* lnw  = (const float*)d_in[3];
    const float* lnb  = (const float*)d_in[4];
    const float* ipw  = (const float*)d_in[5];
    const float* cw   = (const float*)d_in[6];
    const float* cb   = (const float*)d_in[7];
    const float* xpw  = (const float*)d_in[8];
    const float* dtw  = (const float*)d_in[9];
    const float* dtb  = (const float*)d_in[10];
    const float* Alog = (const float*)d_in[11];
    const float* Dp   = (const float*)d_in[12];
    const float* opw  = (const float*)d_in[13];
    const float* opb  = (const float*)d_in[14];
    const float* nw   = (const float*)d_in[15];
    const float* nb   = (const float*)d_in[16];
    const float* clw  = (const float*)d_in[17];
    const float* clb  = (const float*)d_in[18];

    float* ws     = (float*)d_ws;
    float* h      = ws;                       // T*128   = 4,194,304
    float* z      = h    + 4194304;           // T*128   = 4,194,304 (dead after GEMM1
                                              //   -> reused as P|S for the scan)
    float* xz     = z    + 4194304;           // T*512   = 16,777,216
    float* xc     = xz   + 16777216;          // T*256   = 8,388,608
    float* proj   = xc   + 8388608;           // T*40    = 1,310,720
    float* y      = proj + 1310720;           // T*256   = 8,388,608
    float* pooled = y    + 8388608;           // 4096
    float* P      = z;                        // B*NCH*DI*DS = 2,097,152
    float* Sb     = z + 2097152;              // B*NCH*DI*DS = 2,097,152

    k_embed<<<T_, 128, 0, stream>>>(x, Win, bin, h);
    for (int lay = 0; lay < 4; ++lay) {
        k_ln<<<T_ / 4, 256, 0, stream>>>(h, lnw + lay * 128, lnb + lay * 128, z);
        k_gemm<128, 512, false><<<dim3(T_ / 64, 8), 256, 0, stream>>>(
            z, ipw + (size_t)lay * 128 * 512, nullptr, xz);
        k_conv<<<T_, 256, 0, stream>>>(xz, cw + lay * 1024, cb + lay * 256, xc);
        k_xproj<<<T_ / 16, 256, 0, stream>>>(xc, xpw + lay * 256 * 40, proj);
        k_scan_chunk<false><<<dim3(4, NCH_, B_), 256, 0, stream>>>(proj, xc, xz,
            dtw + lay * 2048, dtb + lay * 256, Alog + lay * 4096, Dp + lay * 256,
            P, Sb, y);
        k_scan_combine<<<B_ * 4096 / 256, 256, 0, stream>>>(P, Sb);
        k_scan_chunk<true><<<dim3(4, NCH_, B_), 256, 0, stream>>>(proj, xc, xz,
            dtw + lay * 2048, dtb + lay * 256, Alog + lay * 4096, Dp + lay * 256,
            P, Sb, y);
        k_gemm<256, 128, true><<<dim3(T_ / 64, 2), 256, 0, stream>>>(
            y, opw + (size_t)lay * 256 * 128, opb + lay * 128, h);
    }
    k_pool<<<32, 128, 0, stream>>>(h, pooled);
    k_head<<<32, 128, 0, stream>>>(pooled, nw, nb, clw, clb, (float*)d_out);
}

// Round 3
// 1127.934 us; speedup vs baseline: 3.0920x; 1.2233x over previous
//
#include <hip/hip_runtime.h>
#include <math.h>

// Problem constants
#define B_  32
#define L_  1024
#define T_  (B_ * L_)       // 32768 tokens
#define DM_ 128
#define DI_ 256
#define DS_ 16
#define DC_ 4
#define DR_ 8
#define NC_ 10
#define CHUNK_ 64
#define NCH_  (L_ / CHUNK_)   // 16 chunks

__device__ __forceinline__ float sigmoidf_(float x) { return 1.0f / (1.0f + __expf(-x)); }
__device__ __forceinline__ float siluf_(float x)    { return x * sigmoidf_(x); }
__device__ __forceinline__ float softplusf_(float x) {
    return (x > 15.0f) ? x : __logf(1.0f + __expf(x));
}
__device__ __forceinline__ float fexp2_(float x) { return __builtin_amdgcn_exp2f(x); }

// ---------------- embed: h[t][m] = sum_c x[b,c,l]*Win[c][m] + bin[m] -------------
__global__ __launch_bounds__(128) void k_embed(const float* __restrict__ x,
        const float* __restrict__ Win, const float* __restrict__ bin,
        float* __restrict__ h) {
    int t = blockIdx.x;               // 0..32767
    int b = t >> 10, l = t & 1023;
    int m = threadIdx.x;
    const float* xb = x + (size_t)b * 3 * 1024 + l;
    float acc = bin[m];
    acc = fmaf(xb[0],    Win[m],        acc);
    acc = fmaf(xb[1024], Win[128 + m],  acc);
    acc = fmaf(xb[2048], Win[256 + m],  acc);
    h[(size_t)t * 128 + m] = acc;
}

// ---------------- layernorm over DM=128, one wave per token ----------------------
__global__ __launch_bounds__(256) void k_ln(const float* __restrict__ h,
        const float* __restrict__ w, const float* __restrict__ b,
        float* __restrict__ z) {
    int wid = threadIdx.x >> 6, lane = threadIdx.x & 63;
    int t = blockIdx.x * 4 + wid;
    const float* hr = h + (size_t)t * 128;
    float2 v = *(const float2*)(hr + lane * 2);
    float s = v.x + v.y, sq = v.x * v.x + v.y * v.y;
#pragma unroll
    for (int off = 1; off < 64; off <<= 1) {
        s += __shfl_xor(s, off);
        sq += __shfl_xor(sq, off);
    }
    float mean = s * (1.0f / 128.0f);
    float var = sq * (1.0f / 128.0f) - mean * mean;
    float rstd = rsqrtf(var + 1e-5f);
    float2 wv = *(const float2*)(w + lane * 2);
    float2 bv = *(const float2*)(b + lane * 2);
    float2 o;
    o.x = (v.x - mean) * rstd * wv.x + bv.x;
    o.y = (v.y - mean) * rstd * wv.y + bv.y;
    *(float2*)(z + (size_t)t * 128 + lane * 2) = o;
}

// ---------------- fp32 tiled GEMM: C[M][N] (+=) A[M][K] @ W[K][N] (+bias) --------
// GATE: A element is y[m][k]*silu(gate[m][k]) with gate at xz[t*512+256+k].
template<int K, int N, bool RESID, bool GATE>
__global__ __launch_bounds__(256) void k_gemm(const float* __restrict__ A,
        const float* __restrict__ G, const float* __restrict__ W,
        const float* __restrict__ bias, float* __restrict__ C) {
    __shared__ float As[64][68];   // As[k][m]
    __shared__ float Bs[64][68];   // Bs[k][n]
    int tid = threadIdx.x;
    int tx = tid & 15, ty = tid >> 4;
    int bm = blockIdx.x, bn = blockIdx.y;
    const float* Ab = A + (size_t)bm * 64 * K;
    const float* Gb = GATE ? (G + (size_t)bm * 64 * 512 + 256) : nullptr;
    const float* Wb = W + bn * 64;
    float acc[4][4] = {};
    for (int k0 = 0; k0 < K; k0 += 64) {
#pragma unroll
        for (int r = 0; r < 4; ++r) {
            int idx = tid + 256 * r;          // 0..1023
            int m = idx >> 4, kq = idx & 15;
            float4 v = *(const float4*)(Ab + (size_t)m * K + k0 + kq * 4);
            if (GATE) {
                float4 g = *(const float4*)(Gb + (size_t)m * 512 + k0 + kq * 4);
                v.x *= siluf_(g.x); v.y *= siluf_(g.y);
                v.z *= siluf_(g.z); v.w *= siluf_(g.w);
            }
            As[kq * 4 + 0][m] = v.x;
            As[kq * 4 + 1][m] = v.y;
            As[kq * 4 + 2][m] = v.z;
            As[kq * 4 + 3][m] = v.w;
        }
#pragma unroll
        for (int r = 0; r < 4; ++r) {
            int idx = tid + 256 * r;
            int k = idx >> 4, nq = idx & 15;
            *(float4*)(&Bs[k][nq * 4]) = *(const float4*)(Wb + (size_t)(k0 + k) * N + nq * 4);
        }
        __syncthreads();
#pragma unroll
        for (int k = 0; k < 64; ++k) {
            float4 a = *(const float4*)(&As[k][ty * 4]);
            float4 bv = *(const float4*)(&Bs[k][tx * 4]);
            float av[4] = {a.x, a.y, a.z, a.w};
            float bb[4] = {bv.x, bv.y, bv.z, bv.w};
#pragma unroll
            for (int i = 0; i < 4; ++i)
#pragma unroll
                for (int j = 0; j < 4; ++j)
                    acc[i][j] = fmaf(av[i], bb[j], acc[i][j]);
        }
        __syncthreads();
    }
    float* Cb = C + (size_t)(bm * 64) * N + bn * 64;
#pragma unroll
    for (int i = 0; i < 4; ++i) {
        int row = ty * 4 + i;
        float4 o;
        o.x = acc[i][0]; o.y = acc[i][1]; o.z = acc[i][2]; o.w = acc[i][3];
        float* cp = Cb + (size_t)row * N + tx * 4;
        if (RESID) {
            float4 c = *(const float4*)cp;
            float4 b4 = *(const float4*)(bias + bn * 64 + tx * 4);
            o.x += c.x + b4.x; o.y += c.y + b4.y;
            o.z += c.z + b4.z; o.w += c.w + b4.w;
        }
        *(float4*)cp = o;
    }
}

// ---------------- causal depthwise conv (width 4) + SiLU -------------------------
__global__ __launch_bounds__(256) void k_conv(const float* __restrict__ xz,
        const float* __restrict__ cw, const float* __restrict__ cb,
        float* __restrict__ xc) {
    int t = blockIdx.x, d = threadIdx.x;
    int l = t & 1023;
    float w0 = cw[d * 4 + 0], w1 = cw[d * 4 + 1], w2 = cw[d * 4 + 2], w3 = cw[d * 4 + 3];
    const float* xp = xz + (size_t)t * 512 + d;
    float acc = cb[d];
    if (l >= 3) acc = fmaf(xp[-3 * 512], w0, acc);
    if (l >= 2) acc = fmaf(xp[-2 * 512], w1, acc);
    if (l >= 1) acc = fmaf(xp[-1 * 512], w2, acc);
    acc = fmaf(xp[0], w3, acc);
    xc[(size_t)t * 256 + d] = siluf_(acc);
}

// ---------------- x_proj + fused delta -------------------------------------------
// proj (B|C only, stride 32) = xc @ xpw[:, 8:40]; delta = softplus(xc@xpw[:, :8]
// @ dtw + dtb) stored as [T][256] (aliases y buffer).
__global__ __launch_bounds__(256) void k_xproj(const float* __restrict__ xc,
        const float* __restrict__ xpw, const float* __restrict__ dtw,
        const float* __restrict__ dtb, float* __restrict__ proj,
        float* __restrict__ delta) {
    __shared__ float xcs[16][257];
    __shared__ float prdt[16][8];
    int tid = threadIdx.x;
    int t0 = blockIdx.x * 16;
#pragma unroll
    for (int r = 0; r < 16; ++r) {
        int idx = r * 256 + tid;
        xcs[idx >> 8][idx & 255] = xc[(size_t)t0 * 256 + idx];
    }
    __syncthreads();
#pragma unroll
    for (int jj = 0; jj < 3; ++jj) {
        int j = jj * 256 + tid;
        if (j < 640) {
            int to = j & 15, c = j >> 4;
            float acc = 0.0f;
#pragma unroll 8
            for (int k = 0; k < 256; ++k) acc = fmaf(xcs[to][k], xpw[k * 40 + c], acc);
            if (c < 8) prdt[to][c] = acc;
            else proj[(size_t)(t0 + to) * 32 + (c - 8)] = acc;
        }
    }
    __syncthreads();
    // delta: thread handles d = tid for all 16 tokens
    float dtwc[8];
#pragma unroll
    for (int r = 0; r < 8; ++r) dtwc[r] = dtw[r * 256 + tid];
    float dtbd = dtb[tid];
#pragma unroll
    for (int to = 0; to < 16; ++to) {
        float acc = dtbd;
#pragma unroll
        for (int r = 0; r < 8; ++r) acc = fmaf(prdt[to][r], dtwc[r], acc);
        delta[(size_t)(t0 + to) * 256 + tid] = softplusf_(acc);
    }
}

// ---------------- chunk-parallel SSM scan ----------------------------------------
// Phase A (FINAL=false): local scan from h=0 -> P (decay), S (local final state).
// Phase B: k_scan_combine -> chunk-start states H (in place of P).
// Phase C (FINAL=true): local scan from H; writes yraw = 0.7*(ssm+u*D)+0.3*u.
// (gate*silu applied later in gemm2's A staging). delta aliases y: staged into
// LDS before y-writes to the same region (block-local, safe).
// grid (4 dgroups, NCH_ chunks, B): 256 threads = 64 d x 4 q-lanes (4 states each).
template<bool FINAL>
__global__ __launch_bounds__(256) void k_scan_chunk(
        const float* __restrict__ proj, const float* __restrict__ xc,
        const float* __restrict__ delta,
        const float* __restrict__ Alog, const float* __restrict__ Dp,
        float* __restrict__ P, float* __restrict__ S,
        float* __restrict__ y) {
    __shared__ float projs[CHUNK_ * 32];      // 8 KiB  (B|C)
    __shared__ float xcs[CHUNK_][64];         // 16 KiB
    __shared__ float dls[CHUNK_][64];         // 16 KiB
    int b = blockIdx.z, c = blockIdx.y, dg = blockIdx.x;
    int tid = threadIdx.x;
    int dl = tid >> 2;                        // 0..63 local d
    int d = dg * 64 + dl;
    int q = tid & 3;

    const float* projC = proj + ((size_t)b * 1024 + c * CHUNK_) * 32;
    const float* xcC   = xc   + ((size_t)b * 1024 + c * CHUNK_) * 256 + dg * 64;
    const float* dlC   = delta+ ((size_t)b * 1024 + c * CHUNK_) * 256 + dg * 64;

    // ---- stage chunk operands into LDS ----
#pragma unroll
    for (int r = 0; r < (CHUNK_ * 32) / 256; ++r)
        projs[r * 256 + tid] = projC[r * 256 + tid];
#pragma unroll
    for (int r = 0; r < (CHUNK_ * 64) / 256; ++r) {
        int i = r * 256 + tid;
        xcs[i >> 6][i & 63] = xcC[(size_t)(i >> 6) * 256 + (i & 63)];
        dls[i >> 6][i & 63] = dlC[(size_t)(i >> 6) * 256 + (i & 63)];
    }

    // ---- per-thread constants ----
    float aa[4];
#pragma unroll
    for (int j = 0; j < 4; ++j)
        aa[j] = -__expf(Alog[d * 16 + q * 4 + j]) * 1.44269504088896f;  // A*log2(e)
    float Dpd = Dp[d];

    size_t psIdx = ((size_t)(b * NCH_ + c)) * 4096 + d * 16 + q * 4;
    float hs[4] = {0.0f, 0.0f, 0.0f, 0.0f};
    if (FINAL) {
        float4 h0 = *(const float4*)(P + psIdx);   // P holds chunk-start H
        hs[0] = h0.x; hs[1] = h0.y; hs[2] = h0.z; hs[3] = h0.w;
    }
    float cumd = 0.0f;

    float* yC = y + ((size_t)b * 1024 + c * CHUNK_) * 256 + dg * 64;

    __syncthreads();
    for (int tt = 0; tt < CHUNK_; ++tt) {
        const float* pr = projs + tt * 32;
        float delta_t = dls[tt][dl];
        float u = xcs[tt][dl];
        float du = delta_t * u;
        if (!FINAL) cumd += delta_t;
        float ys = 0.0f;
#pragma unroll
        for (int j = 0; j < 4; ++j) {
            float dA = fexp2_(delta_t * aa[j]);
            hs[j] = fmaf(dA, hs[j], du * pr[q * 4 + j]);
            if (FINAL) ys = fmaf(hs[j], pr[16 + q * 4 + j], ys);
        }
        if (FINAL) {
            ys += __shfl_xor(ys, 1);
            ys += __shfl_xor(ys, 2);
            if (q == 0) {
                float yv = fmaf(u, Dpd, ys);
                yv = fmaf(0.7f, yv, 0.3f * u);     // Luenberger blend
                yC[(size_t)tt * 256 + dl] = yv;    // raw; gate applied in gemm2
            }
        }
    }
    if (!FINAL) {
        float4 pv, sv;
        pv.x = fexp2_(aa[0] * cumd); pv.y = fexp2_(aa[1] * cumd);
        pv.z = fexp2_(aa[2] * cumd); pv.w = fexp2_(aa[3] * cumd);
        sv.x = hs[0]; sv.y = hs[1]; sv.z = hs[2]; sv.w = hs[3];
        *(float4*)(P + psIdx) = pv;
        *(float4*)(S + psIdx) = sv;
    }
}

// ---------------- combine chunk aggregates: H_{c+1} = P_c*H_c + S_c --------------
__global__ __launch_bounds__(256) void k_scan_combine(float* __restrict__ P,
        const float* __restrict__ S) {
    int idx = blockIdx.x * 256 + threadIdx.x;   // b*4096 + d*16 + s
    int b = idx >> 12, rem = idx & 4095;
    float h = 0.0f;
#pragma unroll
    for (int c = 0; c < NCH_; ++c) {
        size_t base = ((size_t)(b * NCH_ + c)) * 4096 + rem;
        float p = P[base];
        float s = S[base];
        P[base] = h;                  // chunk-start state for chunk c
        h = fmaf(p, h, s);
    }
}

// ---------------- mean-pool over L ----------------------------------------------
__global__ __launch_bounds__(128) void k_pool(const float* __restrict__ h,
        float* __restrict__ pooled) {
    int b = blockIdx.x, m = threadIdx.x;
    const float* hb = h + (size_t)b * 1024 * 128 + m;
    float acc = 0.0f;
    for (int l = 0; l < 1024; ++l) acc += hb[(size_t)l * 128];
    pooled[b * 128 + m] = acc * (1.0f / 1024.0f);
}

// ---------------- final LN + classifier -----------------------------------------
__global__ __launch_bounds__(128) void k_head(const float* __restrict__ pooled,
        const float* __restrict__ nw, const float* __restrict__ nb,
        const float* __restrict__ cw, const float* __restrict__ cb,
        float* __restrict__ out) {
    __shared__ float zs[128];
    __shared__ float red[128];
    int b = blockIdx.x, m = threadIdx.x;
    float v = pooled[b * 128 + m];
    red[m] = v;
    __syncthreads();
    for (int off = 64; off; off >>= 1) {
        if (m < off) red[m] += red[m + off];
        __syncthreads();
    }
    float mean = red[0] * (1.0f / 128.0f);
    __syncthreads();
    float dv = v - mean;
    red[m] = dv * dv;
    __syncthreads();
    for (int off = 64; off; off >>= 1) {
        if (m < off) red[m] += red[m + off];
        __syncthreads();
    }
    float rstd = rsqrtf(red[0] * (1.0f / 128.0f) + 1e-5f);
    zs[m] = dv * rstd * nw[m] + nb[m];
    __syncthreads();
    if (m < NC_) {
        float acc = cb[m];
#pragma unroll 8
        for (int k = 0; k < 128; ++k) acc = fmaf(zs[k], cw[k * 10 + m], acc);
        out[b * 10 + m] = acc;
    }
}

extern "C" void kernel_launch(void* const* d_in, const int* in_sizes, int n_in,
                              void* d_out, int out_size, void* d_ws, size_t ws_size,
                              hipStream_t stream) {
    const float* x    = (const float*)d_in[0];
    const float* Win  = (const float*)d_in[1];
    const float* bin  = (const float*)d_in[2];
    const float* lnw  = (const float*)d_in[3];
    const float* lnb  = (const float*)d_in[4];
    const float* ipw  = (const float*)d_in[5];
    const float* cw   = (const float*)d_in[6];
    const float* cb   = (const float*)d_in[7];
    const float* xpw  = (const float*)d_in[8];
    const float* dtw  = (const float*)d_in[9];
    const float* dtb  = (const float*)d_in[10];
    const float* Alog = (const float*)d_in[11];
    const float* Dp   = (const float*)d_in[12];
    const float* opw  = (const float*)d_in[13];
    const float* opb  = (const float*)d_in[14];
    const float* nw   = (const float*)d_in[15];
    const float* nb   = (const float*)d_in[16];
    const float* clw  = (const float*)d_in[17];
    const float* clb  = (const float*)d_in[18];

    float* ws     = (float*)d_ws;
    float* h      = ws;                       // T*128   = 4,194,304
    float* z      = h    + 4194304;           // T*128   (dead after GEMM1 -> P|S)
    float* xz     = z    + 4194304;           // T*512   = 16,777,216
    float* xc     = xz   + 16777216;          // T*256   = 8,388,608
    float* proj   = xc   + 8388608;           // T*32    = 1,048,576
    float* y      = proj + 1310720;           // T*256   = 8,388,608 (also delta)
    float* pooled = y    + 8388608;           // 4096
    float* P      = z;                        // B*NCH*DI*DS = 2,097,152
    float* Sb     = z + 2097152;              // B*NCH*DI*DS = 2,097,152
    float* delta  = y;                        // alias (see k_scan_chunk comment)

    k_embed<<<T_, 128, 0, stream>>>(x, Win, bin, h);
    for (int lay = 0; lay < 4; ++lay) {
        k_ln<<<T_ / 4, 256, 0, stream>>>(h, lnw + lay * 128, lnb + lay * 128, z);
        k_gemm<128, 512, false, false><<<dim3(T_ / 64, 8), 256, 0, stream>>>(
            z, nullptr, ipw + (size_t)lay * 128 * 512, nullptr, xz);
        k_conv<<<T_, 256, 0, stream>>>(xz, cw + lay * 1024, cb + lay * 256, xc);
        k_xproj<<<T_ / 16, 256, 0, stream>>>(xc, xpw + lay * 256 * 40,
            dtw + lay * 2048, dtb + lay * 256, proj, delta);
        k_scan_chunk<false><<<dim3(4, NCH_, B_), 256, 0, stream>>>(proj, xc, delta,
            Alog + lay * 4096, Dp + lay * 256, P, Sb, y);
        k_scan_combine<<<B_ * 4096 / 256, 256, 0, stream>>>(P, Sb);
        k_scan_chunk<true><<<dim3(4, NCH_, B_), 256, 0, stream>>>(proj, xc, delta,
            Alog + lay * 4096, Dp + lay * 256, P, Sb, y);
        k_gemm<256, 128, true, true><<<dim3(T_ / 64, 2), 256, 0, stream>>>(
            y, xz, opw + (size_t)lay * 256 * 128, opb + lay * 128, h);
    }
    k_pool<<<32, 128, 0, stream>>>(h, pooled);
    k_head<<<32, 128, 0, stream>>>(pooled, nw, nb, clw, clb, (float*)d_out);
}

// Round 4
// 848.469 us; speedup vs baseline: 4.1105x; 1.3294x over previous
//
#include <hip/hip_runtime.h>
#include <math.h>

// Problem constants
#define B_  32
#define L_  1024
#define T_  (B_ * L_)       // 32768 tokens
#define DM_ 128
#define DI_ 256
#define DS_ 16
#define DC_ 4
#define DR_ 8
#define NC_ 10
#define CHUNK_ 64
#define NCH_  (L_ / CHUNK_)   // 16 chunks

typedef __bf16 bf16x8 __attribute__((ext_vector_type(8)));
typedef __bf16 bf16x2 __attribute__((ext_vector_type(2)));
typedef float f32x4 __attribute__((ext_vector_type(4)));

__device__ __forceinline__ float sigmoidf_(float x) { return 1.0f / (1.0f + __expf(-x)); }
__device__ __forceinline__ float siluf_(float x)    { return x * sigmoidf_(x); }
__device__ __forceinline__ float softplusf_(float x) {
    return (x > 15.0f) ? x : __logf(1.0f + __expf(x));
}
__device__ __forceinline__ float fexp2_(float x) { return __builtin_amdgcn_exp2f(x); }

// ---------------- embed -----------------------------------------------------------
__global__ __launch_bounds__(128) void k_embed(const float* __restrict__ x,
        const float* __restrict__ Win, const float* __restrict__ bin,
        float* __restrict__ h) {
    int t = blockIdx.x;
    int b = t >> 10, l = t & 1023;
    int m = threadIdx.x;
    const float* xb = x + (size_t)b * 3 * 1024 + l;
    float acc = bin[m];
    acc = fmaf(xb[0],    Win[m],        acc);
    acc = fmaf(xb[1024], Win[128 + m],  acc);
    acc = fmaf(xb[2048], Win[256 + m],  acc);
    h[(size_t)t * 128 + m] = acc;
}

// ---------------- weight prep: transpose + bf16 convert ---------------------------
// wt1[lay][n<512][k<128] = ipw[lay][k][n]; wt2[lay][n<128][k<256] = opw[lay][k][n]
__global__ __launch_bounds__(256) void k_prep_w(const float* __restrict__ ipw,
        const float* __restrict__ opw, __bf16* __restrict__ wt1,
        __bf16* __restrict__ wt2) {
    int i = blockIdx.x * 256 + threadIdx.x;          // < 262144
    {
        int lay = i >> 16, rem = i & 65535, n = rem >> 7, k = rem & 127;
        wt1[i] = (__bf16)ipw[lay * 65536 + k * 512 + n];
    }
    if (i < 4 * 128 * 256) {
        int lay = i >> 15, rem = i & 32767, n = rem >> 8, k = rem & 255;
        wt2[i] = (__bf16)opw[lay * 32768 + k * 128 + n];
    }
}

// ---------------- layernorm -> bf16 ----------------------------------------------
__global__ __launch_bounds__(256) void k_ln(const float* __restrict__ h,
        const float* __restrict__ w, const float* __restrict__ b,
        __bf16* __restrict__ z) {
    int wid = threadIdx.x >> 6, lane = threadIdx.x & 63;
    int t = blockIdx.x * 4 + wid;
    const float* hr = h + (size_t)t * 128;
    float2 v = *(const float2*)(hr + lane * 2);
    float s = v.x + v.y, sq = v.x * v.x + v.y * v.y;
#pragma unroll
    for (int off = 1; off < 64; off <<= 1) {
        s += __shfl_xor(s, off);
        sq += __shfl_xor(sq, off);
    }
    float mean = s * (1.0f / 128.0f);
    float var = sq * (1.0f / 128.0f) - mean * mean;
    float rstd = rsqrtf(var + 1e-5f);
    float2 wv = *(const float2*)(w + lane * 2);
    float2 bv = *(const float2*)(b + lane * 2);
    bf16x2 o;
    o.x = (__bf16)((v.x - mean) * rstd * wv.x + bv.x);
    o.y = (__bf16)((v.y - mean) * rstd * wv.y + bv.y);
    *(bf16x2*)(z + (size_t)t * 128 + lane * 2) = o;
}

// ---------------- bf16 MFMA GEMM: C[M][N] = A[M][K] @ Wt[N][K]^T (+bias+resid) ----
// 128x128 tile, BK=128, 256 threads = 4 waves (2x2), 4x4 16x16x32 frags per wave.
// XOR-swizzled LDS (16B slot ^= row&7) -> conflict-free ds_read_b128.
// GATE: A element = Yf[m][k] * silu(G[m*512 + 256 + k]) cast to bf16.
template<int K, int N, bool RESID, bool GATE>
__global__ __launch_bounds__(256) void k_gemm_mfma(
        const __bf16* __restrict__ A, const float* __restrict__ Yf,
        const float* __restrict__ G, const __bf16* __restrict__ Wt,
        const float* __restrict__ bias, float* __restrict__ C) {
    __shared__ __bf16 As[128 * 128];
    __shared__ __bf16 Bs[128 * 128];
    int tid = threadIdx.x;
    int bm = blockIdx.x, bn = blockIdx.y;
    int lane = tid & 63, wid = tid >> 6;
    int wr = wid >> 1, wc = wid & 1;
    int lr = lane & 15, lg = lane >> 4;

    f32x4 acc[4][4] = {};

    for (int k0 = 0; k0 < K; k0 += 128) {
        // ---- stage A tile (swizzled) ----
#pragma unroll
        for (int r = 0; r < 8; ++r) {
            int idx = tid + 256 * r;            // 0..2047
            int row = idx >> 4, slot = idx & 15;
            bf16x8 v;
            if (GATE) {
                const float* yp = Yf + (size_t)(bm * 128 + row) * 256 + k0 + slot * 8;
                const float* gp = G + (size_t)(bm * 128 + row) * 512 + 256 + k0 + slot * 8;
                float4 y0 = *(const float4*)yp;
                float4 y1 = *(const float4*)(yp + 4);
                float4 g0 = *(const float4*)gp;
                float4 g1 = *(const float4*)(gp + 4);
                v[0] = (__bf16)(y0.x * siluf_(g0.x));
                v[1] = (__bf16)(y0.y * siluf_(g0.y));
                v[2] = (__bf16)(y0.z * siluf_(g0.z));
                v[3] = (__bf16)(y0.w * siluf_(g0.w));
                v[4] = (__bf16)(y1.x * siluf_(g1.x));
                v[5] = (__bf16)(y1.y * siluf_(g1.y));
                v[6] = (__bf16)(y1.z * siluf_(g1.z));
                v[7] = (__bf16)(y1.w * siluf_(g1.w));
            } else {
                v = *(const bf16x8*)(A + (size_t)(bm * 128 + row) * K + k0 + slot * 8);
            }
            *(bf16x8*)(As + row * 128 + ((slot ^ (row & 7)) * 8)) = v;
        }
        // ---- stage B tile (swizzled): Bs[n][k] from Wt[N][K] ----
#pragma unroll
        for (int r = 0; r < 8; ++r) {
            int idx = tid + 256 * r;
            int row = idx >> 4, slot = idx & 15;
            bf16x8 v = *(const bf16x8*)(Wt + (size_t)(bn * 128 + row) * K + k0 + slot * 8);
            *(bf16x8*)(Bs + row * 128 + ((slot ^ (row & 7)) * 8)) = v;
        }
        __syncthreads();
        // ---- 4 k-steps of 32 ----
#pragma unroll
        for (int ks = 0; ks < 4; ++ks) {
            int slotbase = ks * 4 + lg;
            bf16x8 af[4], bfr[4];
#pragma unroll
            for (int m = 0; m < 4; ++m) {
                int row = wr * 64 + m * 16 + lr;
                af[m] = *(const bf16x8*)(As + row * 128 + ((slotbase ^ (row & 7)) * 8));
            }
#pragma unroll
            for (int n = 0; n < 4; ++n) {
                int rn = wc * 64 + n * 16 + lr;
                bfr[n] = *(const bf16x8*)(Bs + rn * 128 + ((slotbase ^ (rn & 7)) * 8));
            }
#pragma unroll
            for (int m = 0; m < 4; ++m)
#pragma unroll
                for (int n = 0; n < 4; ++n)
                    acc[m][n] = __builtin_amdgcn_mfma_f32_16x16x32_bf16(
                        af[m], bfr[n], acc[m][n], 0, 0, 0);
        }
        __syncthreads();
    }
    // ---- epilogue: D[row=(lane>>4)*4+reg][col=lane&15] ----
#pragma unroll
    for (int m = 0; m < 4; ++m) {
#pragma unroll
        for (int n = 0; n < 4; ++n) {
            int col = bn * 128 + wc * 64 + n * 16 + lr;
            float bv = RESID ? bias[col] : 0.0f;
#pragma unroll
            for (int rg = 0; rg < 4; ++rg) {
                int row = bm * 128 + wr * 64 + m * 16 + lg * 4 + rg;
                float* cp = C + (size_t)row * N + col;
                float v = acc[m][n][rg];
                if (RESID) v += *cp + bv;
                *cp = v;
            }
        }
    }
}

// ---------------- causal depthwise conv (width 4) + SiLU -------------------------
__global__ __launch_bounds__(256) void k_conv(const float* __restrict__ xz,
        const float* __restrict__ cw, const float* __restrict__ cb,
        float* __restrict__ xc) {
    int t = blockIdx.x, d = threadIdx.x;
    int l = t & 1023;
    float w0 = cw[d * 4 + 0], w1 = cw[d * 4 + 1], w2 = cw[d * 4 + 2], w3 = cw[d * 4 + 3];
    const float* xp = xz + (size_t)t * 512 + d;
    float acc = cb[d];
    if (l >= 3) acc = fmaf(xp[-3 * 512], w0, acc);
    if (l >= 2) acc = fmaf(xp[-2 * 512], w1, acc);
    if (l >= 1) acc = fmaf(xp[-1 * 512], w2, acc);
    acc = fmaf(xp[0], w3, acc);
    xc[(size_t)t * 256 + d] = siluf_(acc);
}

// ---------------- x_proj + fused delta -------------------------------------------
__global__ __launch_bounds__(256) void k_xproj(const float* __restrict__ xc,
        const float* __restrict__ xpw, const float* __restrict__ dtw,
        const float* __restrict__ dtb, float* __restrict__ proj,
        float* __restrict__ delta) {
    __shared__ float xcs[16][257];
    __shared__ float prdt[16][8];
    int tid = threadIdx.x;
    int t0 = blockIdx.x * 16;
#pragma unroll
    for (int r = 0; r < 16; ++r) {
        int idx = r * 256 + tid;
        xcs[idx >> 8][idx & 255] = xc[(size_t)t0 * 256 + idx];
    }
    __syncthreads();
#pragma unroll
    for (int jj = 0; jj < 3; ++jj) {
        int j = jj * 256 + tid;
        if (j < 640) {
            int to = j & 15, c = j >> 4;
            float acc = 0.0f;
#pragma unroll 8
            for (int k = 0; k < 256; ++k) acc = fmaf(xcs[to][k], xpw[k * 40 + c], acc);
            if (c < 8) prdt[to][c] = acc;
            else proj[(size_t)(t0 + to) * 32 + (c - 8)] = acc;
        }
    }
    __syncthreads();
    float dtwc[8];
#pragma unroll
    for (int r = 0; r < 8; ++r) dtwc[r] = dtw[r * 256 + tid];
    float dtbd = dtb[tid];
#pragma unroll
    for (int to = 0; to < 16; ++to) {
        float acc = dtbd;
#pragma unroll
        for (int r = 0; r < 8; ++r) acc = fmaf(prdt[to][r], dtwc[r], acc);
        delta[(size_t)(t0 + to) * 256 + tid] = softplusf_(acc);
    }
}

// ---------------- chunk-parallel SSM scan ----------------------------------------
template<bool FINAL>
__global__ __launch_bounds__(256) void k_scan_chunk(
        const float* __restrict__ proj, const float* __restrict__ xc,
        const float* __restrict__ delta,
        const float* __restrict__ Alog, const float* __restrict__ Dp,
        float* __restrict__ P, float* __restrict__ S,
        float* __restrict__ y) {
    __shared__ float projs[CHUNK_ * 32];
    __shared__ float xcs[CHUNK_][64];
    __shared__ float dls[CHUNK_][64];
    int b = blockIdx.z, c = blockIdx.y, dg = blockIdx.x;
    int tid = threadIdx.x;
    int dl = tid >> 2;
    int d = dg * 64 + dl;
    int q = tid & 3;

    const float* projC = proj + ((size_t)b * 1024 + c * CHUNK_) * 32;
    const float* xcC   = xc   + ((size_t)b * 1024 + c * CHUNK_) * 256 + dg * 64;
    const float* dlC   = delta+ ((size_t)b * 1024 + c * CHUNK_) * 256 + dg * 64;

#pragma unroll
    for (int r = 0; r < (CHUNK_ * 32) / 256; ++r)
        projs[r * 256 + tid] = projC[r * 256 + tid];
#pragma unroll
    for (int r = 0; r < (CHUNK_ * 64) / 256; ++r) {
        int i = r * 256 + tid;
        xcs[i >> 6][i & 63] = xcC[(size_t)(i >> 6) * 256 + (i & 63)];
        dls[i >> 6][i & 63] = dlC[(size_t)(i >> 6) * 256 + (i & 63)];
    }

    float aa[4];
#pragma unroll
    for (int j = 0; j < 4; ++j)
        aa[j] = -__expf(Alog[d * 16 + q * 4 + j]) * 1.44269504088896f;
    float Dpd = Dp[d];

    size_t psIdx = ((size_t)(b * NCH_ + c)) * 4096 + d * 16 + q * 4;
    float hs[4] = {0.0f, 0.0f, 0.0f, 0.0f};
    if (FINAL) {
        float4 h0 = *(const float4*)(P + psIdx);
        hs[0] = h0.x; hs[1] = h0.y; hs[2] = h0.z; hs[3] = h0.w;
    }
    float cumd = 0.0f;

    float* yC = y + ((size_t)b * 1024 + c * CHUNK_) * 256 + dg * 64;

    __syncthreads();
    for (int tt = 0; tt < CHUNK_; ++tt) {
        const float* pr = projs + tt * 32;
        float delta_t = dls[tt][dl];
        float u = xcs[tt][dl];
        float du = delta_t * u;
        if (!FINAL) cumd += delta_t;
        float ys = 0.0f;
#pragma unroll
        for (int j = 0; j < 4; ++j) {
            float dA = fexp2_(delta_t * aa[j]);
            hs[j] = fmaf(dA, hs[j], du * pr[q * 4 + j]);
            if (FINAL) ys = fmaf(hs[j], pr[16 + q * 4 + j], ys);
        }
        if (FINAL) {
            ys += __shfl_xor(ys, 1);
            ys += __shfl_xor(ys, 2);
            if (q == 0) {
                float yv = fmaf(u, Dpd, ys);
                yv = fmaf(0.7f, yv, 0.3f * u);
                yC[(size_t)tt * 256 + dl] = yv;
            }
        }
    }
    if (!FINAL) {
        float4 pv, sv;
        pv.x = fexp2_(aa[0] * cumd); pv.y = fexp2_(aa[1] * cumd);
        pv.z = fexp2_(aa[2] * cumd); pv.w = fexp2_(aa[3] * cumd);
        sv.x = hs[0]; sv.y = hs[1]; sv.z = hs[2]; sv.w = hs[3];
        *(float4*)(P + psIdx) = pv;
        *(float4*)(S + psIdx) = sv;
    }
}

// ---------------- combine chunk aggregates ---------------------------------------
__global__ __launch_bounds__(256) void k_scan_combine(float* __restrict__ P,
        const float* __restrict__ S) {
    int idx = blockIdx.x * 256 + threadIdx.x;
    int b = idx >> 12, rem = idx & 4095;
    float h = 0.0f;
#pragma unroll
    for (int c = 0; c < NCH_; ++c) {
        size_t base = ((size_t)(b * NCH_ + c)) * 4096 + rem;
        float p = P[base];
        float s = S[base];
        P[base] = h;
        h = fmaf(p, h, s);
    }
}

// ---------------- mean-pool over L ----------------------------------------------
__global__ __launch_bounds__(128) void k_pool(const float* __restrict__ h,
        float* __restrict__ pooled) {
    int b = blockIdx.x, m = threadIdx.x;
    const float* hb = h + (size_t)b * 1024 * 128 + m;
    float acc = 0.0f;
    for (int l = 0; l < 1024; ++l) acc += hb[(size_t)l * 128];
    pooled[b * 128 + m] = acc * (1.0f / 1024.0f);
}

// ---------------- final LN + classifier -----------------------------------------
__global__ __launch_bounds__(128) void k_head(const float* __restrict__ pooled,
        const float* __restrict__ nw, const float* __restrict__ nb,
        const float* __restrict__ cw, const float* __restrict__ cb,
        float* __restrict__ out) {
    __shared__ float zs[128];
    __shared__ float red[128];
    int b = blockIdx.x, m = threadIdx.x;
    float v = pooled[b * 128 + m];
    red[m] = v;
    __syncthreads();
    for (int off = 64; off; off >>= 1) {
        if (m < off) red[m] += red[m + off];
        __syncthreads();
    }
    float mean = red[0] * (1.0f / 128.0f);
    __syncthreads();
    float dv = v - mean;
    red[m] = dv * dv;
    __syncthreads();
    for (int off = 64; off; off >>= 1) {
        if (m < off) red[m] += red[m + off];
        __syncthreads();
    }
    float rstd = rsqrtf(red[0] * (1.0f / 128.0f) + 1e-5f);
    zs[m] = dv * rstd * nw[m] + nb[m];
    __syncthreads();
    if (m < NC_) {
        float acc = cb[m];
#pragma unroll 8
        for (int k = 0; k < 128; ++k) acc = fmaf(zs[k], cw[k * 10 + m], acc);
        out[b * 10 + m] = acc;
    }
}

extern "C" void kernel_launch(void* const* d_in, const int* in_sizes, int n_in,
                              void* d_out, int out_size, void* d_ws, size_t ws_size,
                              hipStream_t stream) {
    const float* x    = (const float*)d_in[0];
    const float* Win  = (const float*)d_in[1];
    const float* bin  = (const float*)d_in[2];
    const float* lnw  = (const float*)d_in[3];
    const float* lnb  = (const float*)d_in[4];
    const float* ipw  = (const float*)d_in[5];
    const float* cw   = (const float*)d_in[6];
    const float* cb   = (const float*)d_in[7];
    const float* xpw  = (const float*)d_in[8];
    const float* dtw  = (const float*)d_in[9];
    const float* dtb  = (const float*)d_in[10];
    const float* Alog = (const float*)d_in[11];
    const float* Dp   = (const float*)d_in[12];
    const float* opw  = (const float*)d_in[13];
    const float* opb  = (const float*)d_in[14];
    const float* nw   = (const float*)d_in[15];
    const float* nb   = (const float*)d_in[16];
    const float* clw  = (const float*)d_in[17];
    const float* clb  = (const float*)d_in[18];

    float* ws     = (float*)d_ws;
    float* h      = ws;                       // T*128
    float* z      = h    + 4194304;           // T*128 region: zb (bf16), then P|S
    float* xz     = z    + 4194304;           // T*512
    float* xc     = xz   + 16777216;          // T*256
    float* proj   = xc   + 8388608;           // T*32 = 1,048,576
    float* y      = proj + 1310720;           // T*256 (also delta alias)
    float* pooled = y    + 8388608;           // 4096
    __bf16* zb    = (__bf16*)z;               // T*128 bf16 (dead before P/S used)
    float* P      = z;                        // B*NCH*DI*DS
    float* Sb     = z + 2097152;
    float* delta  = y;
    __bf16* wt1   = (__bf16*)(proj + 1048576);  // 4*512*128 bf16 = 131072 floats
    __bf16* wt2   = (__bf16*)(proj + 1048576 + 131072);  // 4*128*256 bf16

    k_prep_w<<<1024, 256, 0, stream>>>(ipw, opw, wt1, wt2);
    k_embed<<<T_, 128, 0, stream>>>(x, Win, bin, h);
    for (int lay = 0; lay < 4; ++lay) {
        k_ln<<<T_ / 4, 256, 0, stream>>>(h, lnw + lay * 128, lnb + lay * 128, zb);
        k_gemm_mfma<128, 512, false, false><<<dim3(T_ / 128, 4), 256, 0, stream>>>(
            zb, nullptr, nullptr, wt1 + (size_t)lay * 65536, nullptr, xz);
        k_conv<<<T_, 256, 0, stream>>>(xz, cw + lay * 1024, cb + lay * 256, xc);
        k_xproj<<<T_ / 16, 256, 0, stream>>>(xc, xpw + lay * 256 * 40,
            dtw + lay * 2048, dtb + lay * 256, proj, delta);
        k_scan_chunk<false><<<dim3(4, NCH_, B_), 256, 0, stream>>>(proj, xc, delta,
            Alog + lay * 4096, Dp + lay * 256, P, Sb, y);
        k_scan_combine<<<B_ * 4096 / 256, 256, 0, stream>>>(P, Sb);
        k_scan_chunk<true><<<dim3(4, NCH_, B_), 256, 0, stream>>>(proj, xc, delta,
            Alog + lay * 4096, Dp + lay * 256, P, Sb, y);
        k_gemm_mfma<256, 128, true, true><<<dim3(T_ / 128, 1), 256, 0, stream>>>(
            nullptr, y, xz, wt2 + (size_t)lay * 32768, opb + lay * 128, h);
    }
    k_pool<<<32, 128, 0, stream>>>(h, pooled);
    k_head<<<32, 128, 0, stream>>>(pooled, nw, nb, clw, clb, (float*)d_out);
}

// Round 5
// 753.831 us; speedup vs baseline: 4.6265x; 1.1255x over previous
//
#include <hip/hip_runtime.h>
#include <math.h>

// Problem constants
#define B_  32
#define L_  1024
#define T_  (B_ * L_)       // 32768 tokens
#define DM_ 128
#define DI_ 256
#define DS_ 16
#define DC_ 4
#define DR_ 8
#define NC_ 10
#define CHUNK_ 64
#define NCH_  (L_ / CHUNK_)   // 16 chunks
#define PSTR_ 288             // projall row stride (bf16): 256 delta | 32 B,C

typedef __bf16 bf16x8 __attribute__((ext_vector_type(8)));
typedef __bf16 bf16x2 __attribute__((ext_vector_type(2)));
typedef float f32x4 __attribute__((ext_vector_type(4)));

__device__ __forceinline__ float sigmoidf_(float x) { return 1.0f / (1.0f + __expf(-x)); }
__device__ __forceinline__ float siluf_(float x)    { return x * sigmoidf_(x); }
__device__ __forceinline__ float softplusf_(float x) {
    return (x > 15.0f) ? x : __logf(1.0f + __expf(x));
}
__device__ __forceinline__ float fexp2_(float x) { return __builtin_amdgcn_exp2f(x); }

// ---------------- embed -----------------------------------------------------------
__global__ __launch_bounds__(128) void k_embed(const float* __restrict__ x,
        const float* __restrict__ Win, const float* __restrict__ bin,
        float* __restrict__ h) {
    int t = blockIdx.x;
    int b = t >> 10, l = t & 1023;
    int m = threadIdx.x;
    const float* xb = x + (size_t)b * 3 * 1024 + l;
    float acc = bin[m];
    acc = fmaf(xb[0],    Win[m],        acc);
    acc = fmaf(xb[1024], Win[128 + m],  acc);
    acc = fmaf(xb[2048], Win[256 + m],  acc);
    h[(size_t)t * 128 + m] = acc;
}

// ---------------- weight prep: transpose + bf16 convert ---------------------------
__global__ __launch_bounds__(256) void k_prep_w(const float* __restrict__ ipw,
        const float* __restrict__ opw, __bf16* __restrict__ wt1,
        __bf16* __restrict__ wt2) {
    int i = blockIdx.x * 256 + threadIdx.x;          // < 262144
    {
        int lay = i >> 16, rem = i & 65535, n = rem >> 7, k = rem & 127;
        wt1[i] = (__bf16)ipw[lay * 65536 + k * 512 + n];
    }
    if (i < 4 * 128 * 256) {
        int lay = i >> 15, rem = i & 32767, n = rem >> 8, k = rem & 255;
        wt2[i] = (__bf16)opw[lay * 32768 + k * 128 + n];
    }
}

// ---------------- Wcat prep: [lay][n<384][k<256] ----------------------------------
// n<256:   Wdelta[k][n] = sum_r xpw[k][r] * dtw[r][n]   (delta pre-softplus map)
// 256-287: xpw[k][8 + (n-256)]                          (B,C columns)
// >=288:   0 (pad)
__global__ __launch_bounds__(256) void k_prep_wcat(const float* __restrict__ xpw,
        const float* __restrict__ dtw, __bf16* __restrict__ wcat) {
    int blk = blockIdx.x;              // lay*384 + n
    int lay = blk / 384, n = blk % 384;
    int k = threadIdx.x;
    float v;
    if (n < 256) {
        float acc = 0.0f;
#pragma unroll
        for (int r = 0; r < 8; ++r)
            acc = fmaf(xpw[lay * 10240 + k * 40 + r], dtw[lay * 2048 + r * 256 + n], acc);
        v = acc;
    } else if (n < 288) {
        v = xpw[lay * 10240 + k * 40 + (n - 248)];   // col 8 + (n-256)
    } else {
        v = 0.0f;
    }
    wcat[(size_t)blk * 256 + k] = (__bf16)v;
}

// ---------------- layernorm -> bf16 ----------------------------------------------
__global__ __launch_bounds__(256) void k_ln(const float* __restrict__ h,
        const float* __restrict__ w, const float* __restrict__ b,
        __bf16* __restrict__ z) {
    int wid = threadIdx.x >> 6, lane = threadIdx.x & 63;
    int t = blockIdx.x * 4 + wid;
    const float* hr = h + (size_t)t * 128;
    float2 v = *(const float2*)(hr + lane * 2);
    float s = v.x + v.y, sq = v.x * v.x + v.y * v.y;
#pragma unroll
    for (int off = 1; off < 64; off <<= 1) {
        s += __shfl_xor(s, off);
        sq += __shfl_xor(sq, off);
    }
    float mean = s * (1.0f / 128.0f);
    float var = sq * (1.0f / 128.0f) - mean * mean;
    float rstd = rsqrtf(var + 1e-5f);
    float2 wv = *(const float2*)(w + lane * 2);
    float2 bv = *(const float2*)(b + lane * 2);
    bf16x2 o;
    o.x = (__bf16)((v.x - mean) * rstd * wv.x + bv.x);
    o.y = (__bf16)((v.y - mean) * rstd * wv.y + bv.y);
    *(bf16x2*)(z + (size_t)t * 128 + lane * 2) = o;
}

// ---------------- bf16 MFMA GEMM -------------------------------------------------
// C[M][N] = A[M][K] @ Wt[N][K]^T. 128x128 tile, BK=128, 4 waves (2x2), 4x4 frags.
// XOR-swizzled LDS -> conflict-free ds_read_b128.
// MODE 0: store bf16 to Cb (row stride N)                         [gemm1 -> xzb]
// MODE 1: col<256: softplus(acc+bias[col]) bf16; col<288 raw bf16; else skip;
//         Cb row stride PSTR_                                      [xproj -> projall]
// MODE 2: Cf[row][col] += acc + bias[col] (f32 resid, stride N)    [gemm2 -> h]
// GATE: A element = f32(A[m][k]) * silu(f32(G[m*512+256+k])), bf16 [gemm2 input]
template<int K, int N, int MODE, bool GATE>
__global__ __launch_bounds__(256) void k_gemm_mfma(
        const __bf16* __restrict__ A, const __bf16* __restrict__ G,
        const __bf16* __restrict__ Wt, const float* __restrict__ bias,
        float* __restrict__ Cf, __bf16* __restrict__ Cb) {
    __shared__ __bf16 As[128 * 128];
    __shared__ __bf16 Bs[128 * 128];
    int tid = threadIdx.x;
    int bm = blockIdx.x, bn = blockIdx.y;
    int lane = tid & 63, wid = tid >> 6;
    int wr = wid >> 1, wc = wid & 1;
    int lr = lane & 15, lg = lane >> 4;

    f32x4 acc[4][4] = {};

    for (int k0 = 0; k0 < K; k0 += 128) {
#pragma unroll
        for (int r = 0; r < 8; ++r) {
            int idx = tid + 256 * r;            // 0..2047
            int row = idx >> 4, slot = idx & 15;
            bf16x8 v;
            if (GATE) {
                int m = bm * 128 + row;
                bf16x8 yv = *(const bf16x8*)(A + (size_t)m * K + k0 + slot * 8);
                bf16x8 gv = *(const bf16x8*)(G + (size_t)m * 512 + 256 + k0 + slot * 8);
#pragma unroll
                for (int j = 0; j < 8; ++j)
                    v[j] = (__bf16)((float)yv[j] * siluf_((float)gv[j]));
            } else {
                v = *(const bf16x8*)(A + (size_t)(bm * 128 + row) * K + k0 + slot * 8);
            }
            *(bf16x8*)(As + row * 128 + ((slot ^ (row & 7)) * 8)) = v;
        }
#pragma unroll
        for (int r = 0; r < 8; ++r) {
            int idx = tid + 256 * r;
            int row = idx >> 4, slot = idx & 15;
            bf16x8 v = *(const bf16x8*)(Wt + (size_t)(bn * 128 + row) * K + k0 + slot * 8);
            *(bf16x8*)(Bs + row * 128 + ((slot ^ (row & 7)) * 8)) = v;
        }
        __syncthreads();
#pragma unroll
        for (int ks = 0; ks < 4; ++ks) {
            int slotbase = ks * 4 + lg;
            bf16x8 af[4], bfr[4];
#pragma unroll
            for (int m = 0; m < 4; ++m) {
                int row = wr * 64 + m * 16 + lr;
                af[m] = *(const bf16x8*)(As + row * 128 + ((slotbase ^ (row & 7)) * 8));
            }
#pragma unroll
            for (int n = 0; n < 4; ++n) {
                int rn = wc * 64 + n * 16 + lr;
                bfr[n] = *(const bf16x8*)(Bs + rn * 128 + ((slotbase ^ (rn & 7)) * 8));
            }
#pragma unroll
            for (int m = 0; m < 4; ++m)
#pragma unroll
                for (int n = 0; n < 4; ++n)
                    acc[m][n] = __builtin_amdgcn_mfma_f32_16x16x32_bf16(
                        af[m], bfr[n], acc[m][n], 0, 0, 0);
        }
        __syncthreads();
    }
    // ---- epilogue: D[row=(lane>>4)*4+reg][col=lane&15] ----
#pragma unroll
    for (int m = 0; m < 4; ++m) {
#pragma unroll
        for (int n = 0; n < 4; ++n) {
            int col = bn * 128 + wc * 64 + n * 16 + lr;
            float bv = (MODE == 2) ? bias[col] : 0.0f;
            float dtbv = (MODE == 1 && col < 256) ? bias[col] : 0.0f;
#pragma unroll
            for (int rg = 0; rg < 4; ++rg) {
                int row = bm * 128 + wr * 64 + m * 16 + lg * 4 + rg;
                float v = acc[m][n][rg];
                if (MODE == 0) {
                    Cb[(size_t)row * N + col] = (__bf16)v;
                } else if (MODE == 1) {
                    if (col < 256)
                        Cb[(size_t)row * PSTR_ + col] = (__bf16)softplusf_(v + dtbv);
                    else if (col < 288)
                        Cb[(size_t)row * PSTR_ + col] = (__bf16)v;
                } else {
                    float* cp = Cf + (size_t)row * N + col;
                    *cp = *cp + v + bv;
                }
            }
        }
    }
}

// ---------------- causal depthwise conv (width 4) + SiLU -------------------------
__global__ __launch_bounds__(256) void k_conv(const __bf16* __restrict__ xzb,
        const float* __restrict__ cw, const float* __restrict__ cb,
        float* __restrict__ xc, __bf16* __restrict__ xcb) {
    int t = blockIdx.x, d = threadIdx.x;
    int l = t & 1023;
    float w0 = cw[d * 4 + 0], w1 = cw[d * 4 + 1], w2 = cw[d * 4 + 2], w3 = cw[d * 4 + 3];
    const __bf16* xp = xzb + (size_t)t * 512 + d;
    float acc = cb[d];
    if (l >= 3) acc = fmaf((float)xp[-3 * 512], w0, acc);
    if (l >= 2) acc = fmaf((float)xp[-2 * 512], w1, acc);
    if (l >= 1) acc = fmaf((float)xp[-1 * 512], w2, acc);
    acc = fmaf((float)xp[0], w3, acc);
    float v = siluf_(acc);
    xc[(size_t)t * 256 + d] = v;
    xcb[(size_t)t * 256 + d] = (__bf16)v;
}

// ---------------- chunk-parallel SSM scan ----------------------------------------
// projall[t][0..255]=delta(d), [256..271]=B, [272..287]=C (bf16, stride PSTR_).
template<bool FINAL>
__global__ __launch_bounds__(256) void k_scan_chunk(
        const __bf16* __restrict__ projall, const float* __restrict__ xc,
        const float* __restrict__ Alog, const float* __restrict__ Dp,
        float* __restrict__ P, float* __restrict__ S,
        __bf16* __restrict__ yb) {
    __shared__ float projs[CHUNK_ * 32];      // B|C as f32
    __shared__ float xcs[CHUNK_][64];
    __shared__ float dls[CHUNK_][64];
    int b = blockIdx.z, c = blockIdx.y, dg = blockIdx.x;
    int tid = threadIdx.x;
    int dl = tid >> 2;
    int d = dg * 64 + dl;
    int q = tid & 3;

    const __bf16* projC = projall + ((size_t)b * 1024 + c * CHUNK_) * PSTR_;
    const float* xcC    = xc + ((size_t)b * 1024 + c * CHUNK_) * 256 + dg * 64;

    // ---- stage: BC (64x32), delta slice (64x64), xc slice (64x64) ----
    {
        int t = tid >> 2, c8 = (tid & 3) * 8;
        bf16x8 v = *(const bf16x8*)(projC + (size_t)t * PSTR_ + 256 + c8);
#pragma unroll
        for (int j = 0; j < 8; ++j) projs[t * 32 + c8 + j] = (float)v[j];
        int s0 = (tid & 3) * 16;
        bf16x8 v0 = *(const bf16x8*)(projC + (size_t)t * PSTR_ + dg * 64 + s0);
        bf16x8 v1 = *(const bf16x8*)(projC + (size_t)t * PSTR_ + dg * 64 + s0 + 8);
#pragma unroll
        for (int j = 0; j < 8; ++j) {
            dls[t][s0 + j] = (float)v0[j];
            dls[t][s0 + 8 + j] = (float)v1[j];
        }
#pragma unroll
        for (int j = 0; j < 4; ++j) {
            float4 xv = *(const float4*)(xcC + (size_t)t * 256 + s0 + j * 4);
            xcs[t][s0 + j * 4 + 0] = xv.x;
            xcs[t][s0 + j * 4 + 1] = xv.y;
            xcs[t][s0 + j * 4 + 2] = xv.z;
            xcs[t][s0 + j * 4 + 3] = xv.w;
        }
    }

    float aa[4];
#pragma unroll
    for (int j = 0; j < 4; ++j)
        aa[j] = -__expf(Alog[d * 16 + q * 4 + j]) * 1.44269504088896f;
    float Dpd = Dp[d];

    size_t psIdx = ((size_t)(b * NCH_ + c)) * 4096 + d * 16 + q * 4;
    float hs[4] = {0.0f, 0.0f, 0.0f, 0.0f};
    if (FINAL) {
        float4 h0 = *(const float4*)(P + psIdx);
        hs[0] = h0.x; hs[1] = h0.y; hs[2] = h0.z; hs[3] = h0.w;
    }
    float cumd = 0.0f;

    __bf16* yC = yb + ((size_t)b * 1024 + c * CHUNK_) * 256 + dg * 64;

    __syncthreads();
    for (int tt = 0; tt < CHUNK_; ++tt) {
        const float* pr = projs + tt * 32;
        float delta_t = dls[tt][dl];
        float u = xcs[tt][dl];
        float du = delta_t * u;
        if (!FINAL) cumd += delta_t;
        float ys = 0.0f;
#pragma unroll
        for (int j = 0; j < 4; ++j) {
            float dA = fexp2_(delta_t * aa[j]);
            hs[j] = fmaf(dA, hs[j], du * pr[q * 4 + j]);
            if (FINAL) ys = fmaf(hs[j], pr[16 + q * 4 + j], ys);
        }
        if (FINAL) {
            ys += __shfl_xor(ys, 1);
            ys += __shfl_xor(ys, 2);
            if (q == 0) {
                float yv = fmaf(u, Dpd, ys);
                yv = fmaf(0.7f, yv, 0.3f * u);
                yC[(size_t)tt * 256 + dl] = (__bf16)yv;
            }
        }
    }
    if (!FINAL) {
        float4 pv, sv;
        pv.x = fexp2_(aa[0] * cumd); pv.y = fexp2_(aa[1] * cumd);
        pv.z = fexp2_(aa[2] * cumd); pv.w = fexp2_(aa[3] * cumd);
        sv.x = hs[0]; sv.y = hs[1]; sv.z = hs[2]; sv.w = hs[3];
        *(float4*)(P + psIdx) = pv;
        *(float4*)(S + psIdx) = sv;
    }
}

// ---------------- combine chunk aggregates ---------------------------------------
__global__ __launch_bounds__(256) void k_scan_combine(float* __restrict__ P,
        const float* __restrict__ S) {
    int idx = blockIdx.x * 256 + threadIdx.x;
    int b = idx >> 12, rem = idx & 4095;
    float h = 0.0f;
#pragma unroll
    for (int c = 0; c < NCH_; ++c) {
        size_t base = ((size_t)(b * NCH_ + c)) * 4096 + rem;
        float p = P[base];
        float s = S[base];
        P[base] = h;
        h = fmaf(p, h, s);
    }
}

// ---------------- mean-pool over L ----------------------------------------------
__global__ __launch_bounds__(128) void k_pool(const float* __restrict__ h,
        float* __restrict__ pooled) {
    int b = blockIdx.x, m = threadIdx.x;
    const float* hb = h + (size_t)b * 1024 * 128 + m;
    float acc = 0.0f;
    for (int l = 0; l < 1024; ++l) acc += hb[(size_t)l * 128];
    pooled[b * 128 + m] = acc * (1.0f / 1024.0f);
}

// ---------------- final LN + classifier -----------------------------------------
__global__ __launch_bounds__(128) void k_head(const float* __restrict__ pooled,
        const float* __restrict__ nw, const float* __restrict__ nb,
        const float* __restrict__ cw, const float* __restrict__ cb,
        float* __restrict__ out) {
    __shared__ float zs[128];
    __shared__ float red[128];
    int b = blockIdx.x, m = threadIdx.x;
    float v = pooled[b * 128 + m];
    red[m] = v;
    __syncthreads();
    for (int off = 64; off; off >>= 1) {
        if (m < off) red[m] += red[m + off];
        __syncthreads();
    }
    float mean = red[0] * (1.0f / 128.0f);
    __syncthreads();
    float dv = v - mean;
    red[m] = dv * dv;
    __syncthreads();
    for (int off = 64; off; off >>= 1) {
        if (m < off) red[m] += red[m + off];
        __syncthreads();
    }
    float rstd = rsqrtf(red[0] * (1.0f / 128.0f) + 1e-5f);
    zs[m] = dv * rstd * nw[m] + nb[m];
    __syncthreads();
    if (m < NC_) {
        float acc = cb[m];
#pragma unroll 8
        for (int k = 0; k < 128; ++k) acc = fmaf(zs[k], cw[k * 10 + m], acc);
        out[b * 10 + m] = acc;
    }
}

extern "C" void kernel_launch(void* const* d_in, const int* in_sizes, int n_in,
                              void* d_out, int out_size, void* d_ws, size_t ws_size,
                              hipStream_t stream) {
    const float* x    = (const float*)d_in[0];
    const float* Win  = (const float*)d_in[1];
    const float* bin  = (const float*)d_in[2];
    const float* lnw  = (const float*)d_in[3];
    const float* lnb  = (const float*)d_in[4];
    const float* ipw  = (const float*)d_in[5];
    const float* cw   = (const float*)d_in[6];
    const float* cb   = (const float*)d_in[7];
    const float* xpw  = (const float*)d_in[8];
    const float* dtw  = (const float*)d_in[9];
    const float* dtb  = (const float*)d_in[10];
    const float* Alog = (const float*)d_in[11];
    const float* Dp   = (const float*)d_in[12];
    const float* opw  = (const float*)d_in[13];
    const float* opb  = (const float*)d_in[14];
    const float* nw   = (const float*)d_in[15];
    const float* nb   = (const float*)d_in[16];
    const float* clw  = (const float*)d_in[17];
    const float* clb  = (const float*)d_in[18];

    float* ws = (float*)d_ws;
    float*  h       = ws;                               // 4,194,304 f32
    float*  P       = ws + 4194304;                     // 2,097,152 f32
    float*  Sb      = ws + 6291456;                     // 2,097,152 f32
    __bf16* zb      = (__bf16*)P;                       // T*128 bf16 (dead before P/S)
    __bf16* xzb     = (__bf16*)(ws + 8388608);          // T*512 bf16 (8,388,608 f32 slots)
    float*  xc      = ws + 16777216;                    // T*256 f32
    __bf16* xcb     = (__bf16*)(ws + 25165824);         // T*256 bf16 (4,194,304 slots)
    __bf16* projall = (__bf16*)(ws + 29360128);         // T*288 bf16 (4,718,592 slots)
    __bf16* yb      = (__bf16*)(ws + 34078720);         // T*256 bf16 (4,194,304 slots)
    float*  pooled  = ws + 38273024;                    // 4096
    __bf16* wt1     = (__bf16*)(ws + 38277120);         // 4*512*128 bf16
    __bf16* wt2     = (__bf16*)(ws + 38408192);         // 4*128*256 bf16
    __bf16* wcat    = (__bf16*)(ws + 38473728);         // 4*384*256 bf16

    k_prep_w<<<1024, 256, 0, stream>>>(ipw, opw, wt1, wt2);
    k_prep_wcat<<<4 * 384, 256, 0, stream>>>(xpw, dtw, wcat);
    k_embed<<<T_, 128, 0, stream>>>(x, Win, bin, h);
    for (int lay = 0; lay < 4; ++lay) {
        k_ln<<<T_ / 4, 256, 0, stream>>>(h, lnw + lay * 128, lnb + lay * 128, zb);
        k_gemm_mfma<128, 512, 0, false><<<dim3(T_ / 128, 4), 256, 0, stream>>>(
            zb, nullptr, wt1 + (size_t)lay * 65536, nullptr, nullptr, xzb);
        k_conv<<<T_, 256, 0, stream>>>(xzb, cw + lay * 1024, cb + lay * 256, xc, xcb);
        k_gemm_mfma<256, 384, 1, false><<<dim3(T_ / 128, 3), 256, 0, stream>>>(
            xcb, nullptr, wcat + (size_t)lay * 98304, dtb + lay * 256, nullptr, projall);
        k_scan_chunk<false><<<dim3(4, NCH_, B_), 256, 0, stream>>>(projall, xc,
            Alog + lay * 4096, Dp + lay * 256, P, Sb, yb);
        k_scan_combine<<<B_ * 4096 / 256, 256, 0, stream>>>(P, Sb);
        k_scan_chunk<true><<<dim3(4, NCH_, B_), 256, 0, stream>>>(projall, xc,
            Alog + lay * 4096, Dp + lay * 256, P, Sb, yb);
        k_gemm_mfma<256, 128, 2, true><<<dim3(T_ / 128, 1), 256, 0, stream>>>(
            yb, xzb, wt2 + (size_t)lay * 32768, opb + lay * 128, h, nullptr);
    }
    k_pool<<<32, 128, 0, stream>>>(h, pooled);
    k_head<<<32, 128, 0, stream>>>(pooled, nw, nb, clw, clb, (float*)d_out);
}

// Round 8
// 707.905 us; speedup vs baseline: 4.9267x; 1.0649x over previous
//
#include <hip/hip_runtime.h>
#include <math.h>

// Problem constants
#define B_  32
#define L_  1024
#define T_  (B_ * L_)       // 32768 tokens
#define DM_ 128
#define DI_ 256
#define DS_ 16
#define DC_ 4
#define DR_ 8
#define NC_ 10
#define CHUNK_ 64
#define NCH_  (L_ / CHUNK_)   // 16 chunks
#define PSTR_ 288             // projall row stride (bf16): 256 delta | 32 B,C
#define DROW_ 72              // padded LDS row stride (bf16) for scan tiles

typedef __bf16 bf16x8 __attribute__((ext_vector_type(8)));
typedef __bf16 bf16x4 __attribute__((ext_vector_type(4)));
typedef __bf16 bf16x2 __attribute__((ext_vector_type(2)));
typedef float f32x4 __attribute__((ext_vector_type(4)));

__device__ __forceinline__ float sigmoidf_(float x) { return 1.0f / (1.0f + __expf(-x)); }
__device__ __forceinline__ float siluf_(float x)    { return x * sigmoidf_(x); }
__device__ __forceinline__ float softplusf_(float x) {
    return (x > 15.0f) ? x : __logf(1.0f + __expf(x));
}
__device__ __forceinline__ float fexp2_(float x) { return __builtin_amdgcn_exp2f(x); }

// ---------------- embed -----------------------------------------------------------
__global__ __launch_bounds__(128) void k_embed(const float* __restrict__ x,
        const float* __restrict__ Win, const float* __restrict__ bin,
        float* __restrict__ h) {
    int t = blockIdx.x;
    int b = t >> 10, l = t & 1023;
    int m = threadIdx.x;
    const float* xb = x + (size_t)b * 3 * 1024 + l;
    float acc = bin[m];
    acc = fmaf(xb[0],    Win[m],        acc);
    acc = fmaf(xb[1024], Win[128 + m],  acc);
    acc = fmaf(xb[2048], Win[256 + m],  acc);
    h[(size_t)t * 128 + m] = acc;
}

// ---------------- weight prep: transpose + bf16 convert ---------------------------
__global__ __launch_bounds__(256) void k_prep_w(const float* __restrict__ ipw,
        const float* __restrict__ opw, __bf16* __restrict__ wt1,
        __bf16* __restrict__ wt2) {
    int i = blockIdx.x * 256 + threadIdx.x;          // < 262144
    {
        int lay = i >> 16, rem = i & 65535, n = rem >> 7, k = rem & 127;
        wt1[i] = (__bf16)ipw[lay * 65536 + k * 512 + n];
    }
    if (i < 4 * 128 * 256) {
        int lay = i >> 15, rem = i & 32767, n = rem >> 8, k = rem & 255;
        wt2[i] = (__bf16)opw[lay * 32768 + k * 128 + n];
    }
}

// ---------------- Wcat prep: [lay][n<384][k<256] ----------------------------------
__global__ __launch_bounds__(256) void k_prep_wcat(const float* __restrict__ xpw,
        const float* __restrict__ dtw, __bf16* __restrict__ wcat) {
    int blk = blockIdx.x;              // lay*384 + n
    int lay = blk / 384, n = blk % 384;
    int k = threadIdx.x;
    float v;
    if (n < 256) {
        float acc = 0.0f;
#pragma unroll
        for (int r = 0; r < 8; ++r)
            acc = fmaf(xpw[lay * 10240 + k * 40 + r], dtw[lay * 2048 + r * 256 + n], acc);
        v = acc;
    } else if (n < 288) {
        v = xpw[lay * 10240 + k * 40 + (n - 248)];   // col 8 + (n-256)
    } else {
        v = 0.0f;
    }
    wcat[(size_t)blk * 256 + k] = (__bf16)v;
}

// ---------------- layernorm -> bf16 ----------------------------------------------
__global__ __launch_bounds__(256) void k_ln(const float* __restrict__ h,
        const float* __restrict__ w, const float* __restrict__ b,
        __bf16* __restrict__ z) {
    int wid = threadIdx.x >> 6, lane = threadIdx.x & 63;
    int t = blockIdx.x * 4 + wid;
    const float* hr = h + (size_t)t * 128;
    float2 v = *(const float2*)(hr + lane * 2);
    float s = v.x + v.y, sq = v.x * v.x + v.y * v.y;
#pragma unroll
    for (int off = 1; off < 64; off <<= 1) {
        s += __shfl_xor(s, off);
        sq += __shfl_xor(sq, off);
    }
    float mean = s * (1.0f / 128.0f);
    float var = sq * (1.0f / 128.0f) - mean * mean;
    float rstd = rsqrtf(var + 1e-5f);
    float2 wv = *(const float2*)(w + lane * 2);
    float2 bv = *(const float2*)(b + lane * 2);
    bf16x2 o;
    o.x = (__bf16)((v.x - mean) * rstd * wv.x + bv.x);
    o.y = (__bf16)((v.y - mean) * rstd * wv.y + bv.y);
    *(bf16x2*)(z + (size_t)t * 128 + lane * 2) = o;
}

// ---------------- bf16 MFMA GEMM, BK=64 ------------------------------------------
// C[M][N] = A[M][K] @ Wt[N][K]^T. 128x128 tile, BK=64, 4 waves (2x2), 4x4 frags.
// XOR-swizzled LDS (8 slots of 16B per row, slot ^= row&7) -> conflict-free reads.
// MODE 0: store bf16 to Cb (row stride N)                          [gemm1 -> xzb]
// MODE 1: col<256: softplus(acc+bias) bf16; col<288 raw bf16; skip rest;
//         Cb row stride PSTR_                                       [xproj -> projall]
// MODE 2: Cf[row][col] += acc + bias[col] (f32 resid, stride N)     [gemm2 -> h]
// GATE: A element = f32(A[m][k]) * silu(f32(G[m*512+256+k]))
template<int K, int N, int MODE, bool GATE>
__global__ __launch_bounds__(256) void k_gemm_mfma(
        const __bf16* __restrict__ A, const __bf16* __restrict__ G,
        const __bf16* __restrict__ Wt, const float* __restrict__ bias,
        float* __restrict__ Cf, __bf16* __restrict__ Cb) {
    __shared__ __bf16 As[128 * 64];
    __shared__ __bf16 Bs[128 * 64];
    int tid = threadIdx.x;
    int bm = blockIdx.x, bn = blockIdx.y;
    int lane = tid & 63, wid = tid >> 6;
    int wr = wid >> 1, wc = wid & 1;
    int lr = lane & 15, lg = lane >> 4;

    f32x4 acc[4][4] = {};

    for (int k0 = 0; k0 < K; k0 += 64) {
        // ---- stage A tile (swizzled): 128 rows x 8 slots ----
#pragma unroll
        for (int r = 0; r < 4; ++r) {
            int idx = tid + 256 * r;            // 0..1023
            int row = idx >> 3, slot = idx & 7;
            bf16x8 v;
            if (GATE) {
                int m = bm * 128 + row;
                bf16x8 yv = *(const bf16x8*)(A + (size_t)m * K + k0 + slot * 8);
                bf16x8 gv = *(const bf16x8*)(G + (size_t)m * 512 + 256 + k0 + slot * 8);
#pragma unroll
                for (int j = 0; j < 8; ++j)
                    v[j] = (__bf16)((float)yv[j] * siluf_((float)gv[j]));
            } else {
                v = *(const bf16x8*)(A + (size_t)(bm * 128 + row) * K + k0 + slot * 8);
            }
            *(bf16x8*)(As + row * 64 + ((slot ^ (row & 7)) * 8)) = v;
        }
        // ---- stage B tile (swizzled) ----
#pragma unroll
        for (int r = 0; r < 4; ++r) {
            int idx = tid + 256 * r;
            int row = idx >> 3, slot = idx & 7;
            bf16x8 v = *(const bf16x8*)(Wt + (size_t)(bn * 128 + row) * K + k0 + slot * 8);
            *(bf16x8*)(Bs + row * 64 + ((slot ^ (row & 7)) * 8)) = v;
        }
        __syncthreads();
        // ---- 2 k-steps of 32 ----
#pragma unroll
        for (int ks = 0; ks < 2; ++ks) {
            int slotbase = ks * 4 + lg;
            bf16x8 af[4], bfr[4];
#pragma unroll
            for (int m = 0; m < 4; ++m) {
                int row = wr * 64 + m * 16 + lr;
                af[m] = *(const bf16x8*)(As + row * 64 + ((slotbase ^ (row & 7)) * 8));
            }
#pragma unroll
            for (int n = 0; n < 4; ++n) {
                int rn = wc * 64 + n * 16 + lr;
                bfr[n] = *(const bf16x8*)(Bs + rn * 64 + ((slotbase ^ (rn & 7)) * 8));
            }
#pragma unroll
            for (int m = 0; m < 4; ++m)
#pragma unroll
                for (int n = 0; n < 4; ++n)
                    acc[m][n] = __builtin_amdgcn_mfma_f32_16x16x32_bf16(
                        af[m], bfr[n], acc[m][n], 0, 0, 0);
        }
        __syncthreads();
    }
    // ---- epilogue: D[row=(lane>>4)*4+reg][col=lane&15] ----
#pragma unroll
    for (int m = 0; m < 4; ++m) {
#pragma unroll
        for (int n = 0; n < 4; ++n) {
            int col = bn * 128 + wc * 64 + n * 16 + lr;
            float bv = (MODE == 2) ? bias[col] : 0.0f;
            float dtbv = (MODE == 1 && col < 256) ? bias[col] : 0.0f;
#pragma unroll
            for (int rg = 0; rg < 4; ++rg) {
                int row = bm * 128 + wr * 64 + m * 16 + lg * 4 + rg;
                float v = acc[m][n][rg];
                if (MODE == 0) {
                    Cb[(size_t)row * N + col] = (__bf16)v;
                } else if (MODE == 1) {
                    if (col < 256)
                        Cb[(size_t)row * PSTR_ + col] = (__bf16)softplusf_(v + dtbv);
                    else if (col < 288)
                        Cb[(size_t)row * PSTR_ + col] = (__bf16)v;
                } else {
                    float* cp = Cf + (size_t)row * N + col;
                    *cp = *cp + v + bv;
                }
            }
        }
    }
}

// ---------------- causal depthwise conv (width 4) + SiLU, vectorized -------------
// 4 tokens per block; thread handles 4 channels of one token.
__global__ __launch_bounds__(256) void k_conv(const __bf16* __restrict__ xzb,
        const float* __restrict__ cw, const float* __restrict__ cb,
        __bf16* __restrict__ xcb) {
    int t = blockIdx.x * 4 + (threadIdx.x >> 6);
    int d0 = (threadIdx.x & 63) * 4;
    int l = t & 1023;
    const __bf16* xp = xzb + (size_t)t * 512 + d0;
    float4 wv[4];
#pragma unroll
    for (int j = 0; j < 4; ++j) wv[j] = *(const float4*)(cw + (d0 + j) * 4);
    float acc[4] = {cb[d0], cb[d0 + 1], cb[d0 + 2], cb[d0 + 3]};
#pragma unroll
    for (int k = 0; k < 4; ++k) {         // tap k uses x[t-(3-k)]
        int back = 3 - k;
        if (l >= back) {
            bf16x4 v = *(const bf16x4*)(xp - back * 512);
#pragma unroll
            for (int j = 0; j < 4; ++j)
                acc[j] = fmaf((float)v[j], ((const float*)&wv[j])[k], acc[j]);
        }
    }
    bf16x4 o;
#pragma unroll
    for (int j = 0; j < 4; ++j) o[j] = (__bf16)siluf_(acc[j]);
    *(bf16x4*)(xcb + (size_t)t * 256 + d0) = o;
}

// ---------------- chunk-parallel SSM scan (bf16 inputs) --------------------------
// projall[t][0..255]=delta(d), [256..271]=B, [272..287]=C (bf16, stride PSTR_).
template<bool FINAL>
__global__ __launch_bounds__(256) void k_scan_chunk(
        const __bf16* __restrict__ projall, const __bf16* __restrict__ xcb,
        const float* __restrict__ Alog, const float* __restrict__ Dp,
        float* __restrict__ P, float* __restrict__ S,
        __bf16* __restrict__ yb) {
    __shared__ float projs[CHUNK_ * 33];        // B|C as f32, padded stride
    __shared__ __bf16 dls[CHUNK_ * DROW_];      // delta slice
    __shared__ __bf16 xcs[CHUNK_ * DROW_];      // u slice
    int b = blockIdx.z, c = blockIdx.y, dg = blockIdx.x;
    int tid = threadIdx.x;
    int dl = tid >> 2;
    int d = dg * 64 + dl;
    int q = tid & 3;

    const __bf16* projC = projall + ((size_t)b * 1024 + c * CHUNK_) * PSTR_;
    const __bf16* xcC   = xcb + ((size_t)b * 1024 + c * CHUNK_) * 256 + dg * 64;

    // ---- stage chunk operands ----
    {
        int t = tid >> 2, g4 = tid & 3;
        bf16x8 v = *(const bf16x8*)(projC + (size_t)t * PSTR_ + 256 + g4 * 8);
#pragma unroll
        for (int j = 0; j < 8; ++j) projs[t * 33 + g4 * 8 + j] = (float)v[j];
        int s0 = g4 * 16;
        *(bf16x8*)(dls + t * DROW_ + s0)     = *(const bf16x8*)(projC + (size_t)t * PSTR_ + dg * 64 + s0);
        *(bf16x8*)(dls + t * DROW_ + s0 + 8) = *(const bf16x8*)(projC + (size_t)t * PSTR_ + dg * 64 + s0 + 8);
        *(bf16x8*)(xcs + t * DROW_ + s0)     = *(const bf16x8*)(xcC + (size_t)t * 256 + s0);
        *(bf16x8*)(xcs + t * DROW_ + s0 + 8) = *(const bf16x8*)(xcC + (size_t)t * 256 + s0 + 8);
    }

    float aa[4];
#pragma unroll
    for (int j = 0; j < 4; ++j)
        aa[j] = -__expf(Alog[d * 16 + q * 4 + j]) * 1.44269504088896f;
    float Dpd = Dp[d];

    size_t psIdx = ((size_t)(b * NCH_ + c)) * 4096 + d * 16 + q * 4;
    float hs[4] = {0.0f, 0.0f, 0.0f, 0.0f};
    if (FINAL) {
        float4 h0 = *(const float4*)(P + psIdx);
        hs[0] = h0.x; hs[1] = h0.y; hs[2] = h0.z; hs[3] = h0.w;
    }
    float cumd = 0.0f;

    __bf16* yC = yb + ((size_t)b * 1024 + c * CHUNK_) * 256 + dg * 64;

    __syncthreads();
    for (int tt = 0; tt < CHUNK_; ++tt) {
        const float* pr = projs + tt * 33;
        float delta_t = (float)dls[tt * DROW_ + dl];
        float u = (float)xcs[tt * DROW_ + dl];
        float du = delta_t * u;
        if (!FINAL) cumd += delta_t;
        float ys = 0.0f;
#pragma unroll
        for (int j = 0; j < 4; ++j) {
            float dA = fexp2_(delta_t * aa[j]);
            hs[j] = fmaf(dA, hs[j], du * pr[q * 4 + j]);
            if (FINAL) ys = fmaf(hs[j], pr[16 + q * 4 + j], ys);
        }
        if (FINAL) {
            ys += __shfl_xor(ys, 1);
            ys += __shfl_xor(ys, 2);
            if (q == 0) {
                float yv = fmaf(u, Dpd, ys);
                yv = fmaf(0.7f, yv, 0.3f * u);
                yC[(size_t)tt * 256 + dl] = (__bf16)yv;
            }
        }
    }
    if (!FINAL) {
        float4 pv, sv;
        pv.x = fexp2_(aa[0] * cumd); pv.y = fexp2_(aa[1] * cumd);
        pv.z = fexp2_(aa[2] * cumd); pv.w = fexp2_(aa[3] * cumd);
        sv.x = hs[0]; sv.y = hs[1]; sv.z = hs[2]; sv.w = hs[3];
        *(float4*)(P + psIdx) = pv;
        *(float4*)(S + psIdx) = sv;
    }
}

// ---------------- combine chunk aggregates ---------------------------------------
__global__ __launch_bounds__(256) void k_scan_combine(float* __restrict__ P,
        const float* __restrict__ S) {
    int idx = blockIdx.x * 256 + threadIdx.x;
    int b = idx >> 12, rem = idx & 4095;
    float h = 0.0f;
#pragma unroll
    for (int c = 0; c < NCH_; ++c) {
        size_t base = ((size_t)(b * NCH_ + c)) * 4096 + rem;
        float p = P[base];
        float s = S[base];
        P[base] = h;
        h = fmaf(p, h, s);
    }
}

// ---------------- mean-pool over L: deterministic two-stage ----------------------
// Stage 1: partial[b*8+lc][m] = sum over 128 tokens.
__global__ __launch_bounds__(128) void k_pool(const float* __restrict__ h,
        float* __restrict__ partial) {
    int b = blockIdx.x, lc = blockIdx.y;
    int m = threadIdx.x;
    const float* hb = h + (size_t)b * 131072 + (size_t)lc * 128 * 128 + m;
    float acc = 0.0f;
#pragma unroll 8
    for (int l = 0; l < 128; ++l) acc += hb[(size_t)l * 128];
    partial[((size_t)b * 8 + lc) * 128 + m] = acc;
}

// ---------------- final LN + classifier (sums 8 partials) ------------------------
__global__ __launch_bounds__(128) void k_head(const float* __restrict__ partial,
        const float* __restrict__ nw, const float* __restrict__ nb,
        const float* __restrict__ cw, const float* __restrict__ cb,
        float* __restrict__ out) {
    __shared__ float zs[128];
    __shared__ float red[128];
    int b = blockIdx.x, m = threadIdx.x;
    float v = 0.0f;
#pragma unroll
    for (int lc = 0; lc < 8; ++lc) v += partial[((size_t)b * 8 + lc) * 128 + m];
    v *= (1.0f / 1024.0f);
    red[m] = v;
    __syncthreads();
    for (int off = 64; off; off >>= 1) {
        if (m < off) red[m] += red[m + off];
        __syncthreads();
    }
    float mean = red[0] * (1.0f / 128.0f);
    __syncthreads();
    float dv = v - mean;
    red[m] = dv * dv;
    __syncthreads();
    for (int off = 64; off; off >>= 1) {
        if (m < off) red[m] += red[m + off];
        __syncthreads();
    }
    float rstd = rsqrtf(red[0] * (1.0f / 128.0f) + 1e-5f);
    zs[m] = dv * rstd * nw[m] + nb[m];
    __syncthreads();
    if (m < NC_) {
        float acc = cb[m];
#pragma unroll 8
        for (int k = 0; k < 128; ++k) acc = fmaf(zs[k], cw[k * 10 + m], acc);
        out[b * 10 + m] = acc;
    }
}

extern "C" void kernel_launch(void* const* d_in, const int* in_sizes, int n_in,
                              void* d_out, int out_size, void* d_ws, size_t ws_size,
                              hipStream_t stream) {
    const float* x    = (const float*)d_in[0];
    const float* Win  = (const float*)d_in[1];
    const float* bin  = (const float*)d_in[2];
    const float* lnw  = (const float*)d_in[3];
    const float* lnb  = (const float*)d_in[4];
    const float* ipw  = (const float*)d_in[5];
    const float* cw   = (const float*)d_in[6];
    const float* cb   = (const float*)d_in[7];
    const float* xpw  = (const float*)d_in[8];
    const float* dtw  = (const float*)d_in[9];
    const float* dtb  = (const float*)d_in[10];
    const float* Alog = (const float*)d_in[11];
    const float* Dp   = (const float*)d_in[12];
    const float* opw  = (const float*)d_in[13];
    const float* opb  = (const float*)d_in[14];
    const float* nw   = (const float*)d_in[15];
    const float* nb   = (const float*)d_in[16];
    const float* clw  = (const float*)d_in[17];
    const float* clb  = (const float*)d_in[18];

    // f32-slot offsets (all non-overlapping):
    //   h        [0,        4194304)
    //   P        [4194304,  6291456)   (zb bf16 aliases P; dead before P used)
    //   Sb       [6291456,  8388608)
    //   xzb bf16 [8388608,  16777216)  T*512 bf16 = 8,388,608 slots
    //   xcb bf16 [16777216, 20971520)  T*256 bf16 = 4,194,304 slots
    //   projall  [20971520, 25690112)  T*288 bf16 = 4,718,592 slots
    //   yb bf16  [25690112, 29884416)  T*256 bf16
    //   partial  [29884416, 29917184)  32*8*128 f32
    //   wt1      [29917184, 30048256)  4*512*128 bf16 = 131,072 f32 slots
    //   wt2      [30048256, 30113792)  4*128*256 bf16 =  65,536 f32 slots
    //   wcat     [30113792, 30310400)  4*384*256 bf16 = 196,608 f32 slots
    float* ws = (float*)d_ws;
    float*  h       = ws;
    float*  P       = ws + 4194304;
    float*  Sb      = ws + 6291456;
    __bf16* zb      = (__bf16*)P;
    __bf16* xzb     = (__bf16*)(ws + 8388608);
    __bf16* xcb     = (__bf16*)(ws + 16777216);
    __bf16* projall = (__bf16*)(ws + 20971520);
    __bf16* yb      = (__bf16*)(ws + 25690112);
    float*  partial = ws + 29884416;
    __bf16* wt1     = (__bf16*)(ws + 29917184);
    __bf16* wt2     = (__bf16*)(ws + 30048256);
    __bf16* wcat    = (__bf16*)(ws + 30113792);

    k_prep_w<<<1024, 256, 0, stream>>>(ipw, opw, wt1, wt2);
    k_prep_wcat<<<4 * 384, 256, 0, stream>>>(xpw, dtw, wcat);
    k_embed<<<T_, 128, 0, stream>>>(x, Win, bin, h);
    for (int lay = 0; lay < 4; ++lay) {
        k_ln<<<T_ / 4, 256, 0, stream>>>(h, lnw + lay * 128, lnb + lay * 128, zb);
        k_gemm_mfma<128, 512, 0, false><<<dim3(T_ / 128, 4), 256, 0, stream>>>(
            zb, nullptr, wt1 + (size_t)lay * 65536, nullptr, nullptr, xzb);
        k_conv<<<T_ / 4, 256, 0, stream>>>(xzb, cw + lay * 1024, cb + lay * 256, xcb);
        k_gemm_mfma<256, 384, 1, false><<<dim3(T_ / 128, 3), 256, 0, stream>>>(
            xcb, nullptr, wcat + (size_t)lay * 98304, dtb + lay * 256, nullptr, projall);
        k_scan_chunk<false><<<dim3(4, NCH_, B_), 256, 0, stream>>>(projall, xcb,
            Alog + lay * 4096, Dp + lay * 256, P, Sb, yb);
        k_scan_combine<<<B_ * 4096 / 256, 256, 0, stream>>>(P, Sb);
        k_scan_chunk<true><<<dim3(4, NCH_, B_), 256, 0, stream>>>(projall, xcb,
            Alog + lay * 4096, Dp + lay * 256, P, Sb, yb);
        k_gemm_mfma<256, 128, 2, true><<<dim3(T_ / 128, 1), 256, 0, stream>>>(
            yb, xzb, wt2 + (size_t)lay * 32768, opb + lay * 128, h, nullptr);
    }
    k_pool<<<dim3(32, 8), 128, 0, stream>>>(h, partial);
    k_head<<<32, 128, 0, stream>>>(partial, nw, nb, clw, clb, (float*)d_out);
}

// Round 9
// 664.165 us; speedup vs baseline: 5.2511x; 1.0659x over previous
//
#include <hip/hip_runtime.h>
#include <math.h>

// Problem constants
#define B_  32
#define L_  1024
#define T_  (B_ * L_)       // 32768 tokens
#define DM_ 128
#define DI_ 256
#define DS_ 16
#define DC_ 4
#define DR_ 8
#define NC_ 10
#define CHUNK_ 64
#define NCH_  (L_ / CHUNK_)   // 16 chunks
#define PSTR_ 288             // projall row stride (bf16): 256 delta | 32 B,C
#define DROW_ 72              // padded LDS row stride (bf16) for scan tiles

typedef __bf16 bf16x8 __attribute__((ext_vector_type(8)));
typedef __bf16 bf16x4 __attribute__((ext_vector_type(4)));
typedef __bf16 bf16x2 __attribute__((ext_vector_type(2)));
typedef float f32x4 __attribute__((ext_vector_type(4)));

__device__ __forceinline__ float sigmoidf_(float x) { return 1.0f / (1.0f + __expf(-x)); }
__device__ __forceinline__ float siluf_(float x)    { return x * sigmoidf_(x); }
__device__ __forceinline__ float softplusf_(float x) {
    return (x > 15.0f) ? x : __logf(1.0f + __expf(x));
}
__device__ __forceinline__ float fexp2_(float x) { return __builtin_amdgcn_exp2f(x); }

// async 16B global->LDS (gfx950). dest = wave-uniform base + lane*16.
__device__ __forceinline__ void gload_lds16(const __bf16* g, __bf16* l) {
    __builtin_amdgcn_global_load_lds(
        (const __attribute__((address_space(1))) void*)g,
        (__attribute__((address_space(3))) void*)l, 16, 0, 0);
}

// Stage an R x 64 bf16 tile (row stride `stride`, col offset k0) into LDS with
// XOR-swizzle baked in: LDS (row, sw) holds source (row, sw ^ (row&7)).
// Linear LDS writes (lane x 16B), per-lane pre-swizzled source address.
template<int R>
__device__ __forceinline__ void stage_async(const __bf16* __restrict__ src,
        __bf16* lds, int k0, int stride, int wid, int lane) {
    constexpr int NI = R / 32;          // 16B-instrs per wave (R*8 slots / 64 / 4)
#pragma unroll
    for (int j = 0; j < NI; ++j) {
        int s0 = (wid * NI + j) * 64;
        int s = s0 + lane;
        int row = s >> 3, sw = s & 7;
        int slot = sw ^ (row & 7);
        gload_lds16(src + (size_t)row * stride + k0 + slot * 8, lds + (size_t)s0 * 8);
    }
}

// ---------------- embed -----------------------------------------------------------
__global__ __launch_bounds__(128) void k_embed(const float* __restrict__ x,
        const float* __restrict__ Win, const float* __restrict__ bin,
        float* __restrict__ h) {
    int t = blockIdx.x;
    int b = t >> 10, l = t & 1023;
    int m = threadIdx.x;
    const float* xb = x + (size_t)b * 3 * 1024 + l;
    float acc = bin[m];
    acc = fmaf(xb[0],    Win[m],        acc);
    acc = fmaf(xb[1024], Win[128 + m],  acc);
    acc = fmaf(xb[2048], Win[256 + m],  acc);
    h[(size_t)t * 128 + m] = acc;
}

// ---------------- weight prep: transpose + bf16 convert ---------------------------
__global__ __launch_bounds__(256) void k_prep_w(const float* __restrict__ ipw,
        const float* __restrict__ opw, __bf16* __restrict__ wt1,
        __bf16* __restrict__ wt2) {
    int i = blockIdx.x * 256 + threadIdx.x;          // < 262144
    {
        int lay = i >> 16, rem = i & 65535, n = rem >> 7, k = rem & 127;
        wt1[i] = (__bf16)ipw[lay * 65536 + k * 512 + n];
    }
    if (i < 4 * 128 * 256) {
        int lay = i >> 15, rem = i & 32767, n = rem >> 8, k = rem & 255;
        wt2[i] = (__bf16)opw[lay * 32768 + k * 128 + n];
    }
}

// ---------------- Wcat prep: [lay][n<384][k<256] ----------------------------------
__global__ __launch_bounds__(256) void k_prep_wcat(const float* __restrict__ xpw,
        const float* __restrict__ dtw, __bf16* __restrict__ wcat) {
    int blk = blockIdx.x;              // lay*384 + n
    int lay = blk / 384, n = blk % 384;
    int k = threadIdx.x;
    float v;
    if (n < 256) {
        float acc = 0.0f;
#pragma unroll
        for (int r = 0; r < 8; ++r)
            acc = fmaf(xpw[lay * 10240 + k * 40 + r], dtw[lay * 2048 + r * 256 + n], acc);
        v = acc;
    } else if (n < 288) {
        v = xpw[lay * 10240 + k * 40 + (n - 248)];   // col 8 + (n-256)
    } else {
        v = 0.0f;
    }
    wcat[(size_t)blk * 256 + k] = (__bf16)v;
}

// ---------------- layernorm -> bf16 ----------------------------------------------
__global__ __launch_bounds__(256) void k_ln(const float* __restrict__ h,
        const float* __restrict__ w, const float* __restrict__ b,
        __bf16* __restrict__ z) {
    int wid = threadIdx.x >> 6, lane = threadIdx.x & 63;
    int t = blockIdx.x * 4 + wid;
    const float* hr = h + (size_t)t * 128;
    float2 v = *(const float2*)(hr + lane * 2);
    float s = v.x + v.y, sq = v.x * v.x + v.y * v.y;
#pragma unroll
    for (int off = 1; off < 64; off <<= 1) {
        s += __shfl_xor(s, off);
        sq += __shfl_xor(sq, off);
    }
    float mean = s * (1.0f / 128.0f);
    float var = sq * (1.0f / 128.0f) - mean * mean;
    float rstd = rsqrtf(var + 1e-5f);
    float2 wv = *(const float2*)(w + lane * 2);
    float2 bv = *(const float2*)(b + lane * 2);
    bf16x2 o;
    o.x = (__bf16)((v.x - mean) * rstd * wv.x + bv.x);
    o.y = (__bf16)((v.y - mean) * rstd * wv.y + bv.y);
    *(bf16x2*)(z + (size_t)t * 128 + lane * 2) = o;
}

// ---------------- bf16 MFMA GEMM, BM x 128 tile, BK=64 ---------------------------
// C[M][N] = A[M][K] @ Wt[N][K]^T. 4 waves as 1x4 (wave = BM x 32 cols).
// LDS XOR-swizzled; non-GATE tiles staged via async global_load_lds with
// pre-swizzled source; GATE A staged through registers (needs silu compute).
// MODE 0: store bf16 (stride N)            [gemm1 -> xzb]
// MODE 1: col<256 softplus+bias bf16, col<288 raw bf16, rest skipped;
//         stride PSTR_                      [xproj -> projall]
// MODE 2: Cf += acc + bias (f32, stride N)  [gemm2 -> h]
template<int BM, int K, int N, int MODE, bool GATE>
__global__ __launch_bounds__(256) void k_gemm_mfma(
        const __bf16* __restrict__ A, const __bf16* __restrict__ G,
        const __bf16* __restrict__ Wt, const float* __restrict__ bias,
        float* __restrict__ Cf, __bf16* __restrict__ Cb) {
    static_assert(!GATE || BM == 32, "GATE staging assumes BM=32");
    __shared__ __bf16 As[BM * 64];
    __shared__ __bf16 Bs[128 * 64];
    int tid = threadIdx.x;
    int bm = blockIdx.x, bn = blockIdx.y;
    int lane = tid & 63, wid = tid >> 6;
    int lr = lane & 15, lg = lane >> 4;
    constexpr int MF = BM / 16;

    f32x4 acc[MF][2] = {};
    const __bf16* Asrc = A + (size_t)(bm * BM) * K;
    const __bf16* Bsrc = Wt + (size_t)(bn * 128) * K;

    for (int k0 = 0; k0 < K; k0 += 64) {
        if (GATE) {
            // 256 threads x 8 elems = 32x64 tile
            int row = tid >> 3, slot = tid & 7;
            int m = bm * BM + row;
            bf16x8 yv = *(const bf16x8*)(A + (size_t)m * K + k0 + slot * 8);
            bf16x8 gv = *(const bf16x8*)(G + (size_t)m * 512 + 256 + k0 + slot * 8);
            bf16x8 v;
#pragma unroll
            for (int j = 0; j < 8; ++j)
                v[j] = (__bf16)((float)yv[j] * siluf_((float)gv[j]));
            *(bf16x8*)(As + row * 64 + ((slot ^ (row & 7)) * 8)) = v;
        } else {
            stage_async<BM>(Asrc, As, k0, K, wid, lane);
        }
        stage_async<128>(Bsrc, Bs, k0, K, wid, lane);
        __syncthreads();
#pragma unroll
        for (int ks = 0; ks < 2; ++ks) {
            int slotbase = ks * 4 + lg;
            bf16x8 af[MF], bfr[2];
#pragma unroll
            for (int m = 0; m < MF; ++m) {
                int row = m * 16 + lr;
                af[m] = *(const bf16x8*)(As + row * 64 + ((slotbase ^ (row & 7)) * 8));
            }
#pragma unroll
            for (int n = 0; n < 2; ++n) {
                int rn = wid * 32 + n * 16 + lr;
                bfr[n] = *(const bf16x8*)(Bs + rn * 64 + ((slotbase ^ (rn & 7)) * 8));
            }
#pragma unroll
            for (int m = 0; m < MF; ++m)
#pragma unroll
                for (int n = 0; n < 2; ++n)
                    acc[m][n] = __builtin_amdgcn_mfma_f32_16x16x32_bf16(
                        af[m], bfr[n], acc[m][n], 0, 0, 0);
        }
        __syncthreads();
    }
    // ---- epilogue: D[row=(lane>>4)*4+reg][col=lane&15] ----
#pragma unroll
    for (int m = 0; m < MF; ++m) {
#pragma unroll
        for (int n = 0; n < 2; ++n) {
            int col = bn * 128 + wid * 32 + n * 16 + lr;
            float bv = (MODE == 2) ? bias[col] : 0.0f;
            float dtbv = (MODE == 1 && col < 256) ? bias[col] : 0.0f;
#pragma unroll
            for (int rg = 0; rg < 4; ++rg) {
                int row = bm * BM + m * 16 + lg * 4 + rg;
                float v = acc[m][n][rg];
                if (MODE == 0) {
                    Cb[(size_t)row * N + col] = (__bf16)v;
                } else if (MODE == 1) {
                    if (col < 256)
                        Cb[(size_t)row * PSTR_ + col] = (__bf16)softplusf_(v + dtbv);
                    else if (col < 288)
                        Cb[(size_t)row * PSTR_ + col] = (__bf16)v;
                } else {
                    float* cp = Cf + (size_t)row * N + col;
                    *cp = *cp + v + bv;
                }
            }
        }
    }
}

// ---------------- causal depthwise conv (width 4) + SiLU, vectorized -------------
__global__ __launch_bounds__(256) void k_conv(const __bf16* __restrict__ xzb,
        const float* __restrict__ cw, const float* __restrict__ cb,
        __bf16* __restrict__ xcb) {
    int t = blockIdx.x * 4 + (threadIdx.x >> 6);
    int d0 = (threadIdx.x & 63) * 4;
    int l = t & 1023;
    const __bf16* xp = xzb + (size_t)t * 512 + d0;
    float4 wv[4];
#pragma unroll
    for (int j = 0; j < 4; ++j) wv[j] = *(const float4*)(cw + (d0 + j) * 4);
    float acc[4] = {cb[d0], cb[d0 + 1], cb[d0 + 2], cb[d0 + 3]};
#pragma unroll
    for (int k = 0; k < 4; ++k) {         // tap k uses x[t-(3-k)]
        int back = 3 - k;
        if (l >= back) {
            bf16x4 v = *(const bf16x4*)(xp - back * 512);
#pragma unroll
            for (int j = 0; j < 4; ++j)
                acc[j] = fmaf((float)v[j], ((const float*)&wv[j])[k], acc[j]);
        }
    }
    bf16x4 o;
#pragma unroll
    for (int j = 0; j < 4; ++j) o[j] = (__bf16)siluf_(acc[j]);
    *(bf16x4*)(xcb + (size_t)t * 256 + d0) = o;
}

// ---------------- chunk-parallel SSM scan (bf16 inputs) --------------------------
// projall[t][0..255]=delta(d), [256..271]=B, [272..287]=C (bf16, stride PSTR_).
template<bool FINAL>
__global__ __launch_bounds__(256) void k_scan_chunk(
        const __bf16* __restrict__ projall, const __bf16* __restrict__ xcb,
        const float* __restrict__ Alog, const float* __restrict__ Dp,
        float* __restrict__ P, float* __restrict__ S,
        __bf16* __restrict__ yb) {
    __shared__ float projs[CHUNK_ * 33];        // B|C as f32, padded stride
    __shared__ __bf16 dls[CHUNK_ * DROW_];      // delta slice
    __shared__ __bf16 xcs[CHUNK_ * DROW_];      // u slice
    int b = blockIdx.z, c = blockIdx.y, dg = blockIdx.x;
    int tid = threadIdx.x;
    int dl = tid >> 2;
    int d = dg * 64 + dl;
    int q = tid & 3;

    const __bf16* projC = projall + ((size_t)b * 1024 + c * CHUNK_) * PSTR_;
    const __bf16* xcC   = xcb + ((size_t)b * 1024 + c * CHUNK_) * 256 + dg * 64;

    // ---- stage chunk operands ----
    {
        int t = tid >> 2, g4 = tid & 3;
        bf16x8 v = *(const bf16x8*)(projC + (size_t)t * PSTR_ + 256 + g4 * 8);
#pragma unroll
        for (int j = 0; j < 8; ++j) projs[t * 33 + g4 * 8 + j] = (float)v[j];
        int s0 = g4 * 16;
        *(bf16x8*)(dls + t * DROW_ + s0)     = *(const bf16x8*)(projC + (size_t)t * PSTR_ + dg * 64 + s0);
        *(bf16x8*)(dls + t * DROW_ + s0 + 8) = *(const bf16x8*)(projC + (size_t)t * PSTR_ + dg * 64 + s0 + 8);
        *(bf16x8*)(xcs + t * DROW_ + s0)     = *(const bf16x8*)(xcC + (size_t)t * 256 + s0);
        *(bf16x8*)(xcs + t * DROW_ + s0 + 8) = *(const bf16x8*)(xcC + (size_t)t * 256 + s0 + 8);
    }

    float aa[4];
#pragma unroll
    for (int j = 0; j < 4; ++j)
        aa[j] = -__expf(Alog[d * 16 + q * 4 + j]) * 1.44269504088896f;
    float Dpd = Dp[d];

    size_t psIdx = ((size_t)(b * NCH_ + c)) * 4096 + d * 16 + q * 4;
    float hs[4] = {0.0f, 0.0f, 0.0f, 0.0f};
    if (FINAL) {
        float4 h0 = *(const float4*)(P + psIdx);
        hs[0] = h0.x; hs[1] = h0.y; hs[2] = h0.z; hs[3] = h0.w;
    }
    float cumd = 0.0f;

    __bf16* yC = yb + ((size_t)b * 1024 + c * CHUNK_) * 256 + dg * 64;

    __syncthreads();
    for (int tt = 0; tt < CHUNK_; ++tt) {
        const float* pr = projs + tt * 33;
        float delta_t = (float)dls[tt * DROW_ + dl];
        float u = (float)xcs[tt * DROW_ + dl];
        float du = delta_t * u;
        if (!FINAL) cumd += delta_t;
        float ys = 0.0f;
#pragma unroll
        for (int j = 0; j < 4; ++j) {
            float dA = fexp2_(delta_t * aa[j]);
            hs[j] = fmaf(dA, hs[j], du * pr[q * 4 + j]);
            if (FINAL) ys = fmaf(hs[j], pr[16 + q * 4 + j], ys);
        }
        if (FINAL) {
            ys += __shfl_xor(ys, 1);
            ys += __shfl_xor(ys, 2);
            if (q == 0) {
                float yv = fmaf(u, Dpd, ys);
                yv = fmaf(0.7f, yv, 0.3f * u);
                yC[(size_t)tt * 256 + dl] = (__bf16)yv;
            }
        }
    }
    if (!FINAL) {
        float4 pv, sv;
        pv.x = fexp2_(aa[0] * cumd); pv.y = fexp2_(aa[1] * cumd);
        pv.z = fexp2_(aa[2] * cumd); pv.w = fexp2_(aa[3] * cumd);
        sv.x = hs[0]; sv.y = hs[1]; sv.z = hs[2]; sv.w = hs[3];
        *(float4*)(P + psIdx) = pv;
        *(float4*)(S + psIdx) = sv;
    }
}

// ---------------- combine chunk aggregates ---------------------------------------
__global__ __launch_bounds__(256) void k_scan_combine(float* __restrict__ P,
        const float* __restrict__ S) {
    int idx = blockIdx.x * 256 + threadIdx.x;
    int b = idx >> 12, rem = idx & 4095;
    float h = 0.0f;
#pragma unroll
    for (int c = 0; c < NCH_; ++c) {
        size_t base = ((size_t)(b * NCH_ + c)) * 4096 + rem;
        float p = P[base];
        float s = S[base];
        P[base] = h;
        h = fmaf(p, h, s);
    }
}

// ---------------- mean-pool over L: deterministic two-stage ----------------------
__global__ __launch_bounds__(128) void k_pool(const float* __restrict__ h,
        float* __restrict__ partial) {
    int b = blockIdx.x, lc = blockIdx.y;
    int m = threadIdx.x;
    const float* hb = h + (size_t)b * 131072 + (size_t)lc * 128 * 128 + m;
    float acc = 0.0f;
#pragma unroll 8
    for (int l = 0; l < 128; ++l) acc += hb[(size_t)l * 128];
    partial[((size_t)b * 8 + lc) * 128 + m] = acc;
}

// ---------------- final LN + classifier (sums 8 partials) ------------------------
__global__ __launch_bounds__(128) void k_head(const float* __restrict__ partial,
        const float* __restrict__ nw, const float* __restrict__ nb,
        const float* __restrict__ cw, const float* __restrict__ cb,
        float* __restrict__ out) {
    __shared__ float zs[128];
    __shared__ float red[128];
    int b = blockIdx.x, m = threadIdx.x;
    float v = 0.0f;
#pragma unroll
    for (int lc = 0; lc < 8; ++lc) v += partial[((size_t)b * 8 + lc) * 128 + m];
    v *= (1.0f / 1024.0f);
    red[m] = v;
    __syncthreads();
    for (int off = 64; off; off >>= 1) {
        if (m < off) red[m] += red[m + off];
        __syncthreads();
    }
    float mean = red[0] * (1.0f / 128.0f);
    __syncthreads();
    float dv = v - mean;
    red[m] = dv * dv;
    __syncthreads();
    for (int off = 64; off; off >>= 1) {
        if (m < off) red[m] += red[m + off];
        __syncthreads();
    }
    float rstd = rsqrtf(red[0] * (1.0f / 128.0f) + 1e-5f);
    zs[m] = dv * rstd * nw[m] + nb[m];
    __syncthreads();
    if (m < NC_) {
        float acc = cb[m];
#pragma unroll 8
        for (int k = 0; k < 128; ++k) acc = fmaf(zs[k], cw[k * 10 + m], acc);
        out[b * 10 + m] = acc;
    }
}

extern "C" void kernel_launch(void* const* d_in, const int* in_sizes, int n_in,
                              void* d_out, int out_size, void* d_ws, size_t ws_size,
                              hipStream_t stream) {
    const float* x    = (const float*)d_in[0];
    const float* Win  = (const float*)d_in[1];
    const float* bin  = (const float*)d_in[2];
    const float* lnw  = (const float*)d_in[3];
    const float* lnb  = (const float*)d_in[4];
    const float* ipw  = (const float*)d_in[5];
    const float* cw   = (const float*)d_in[6];
    const float* cb   = (const float*)d_in[7];
    const float* xpw  = (const float*)d_in[8];
    const float* dtw  = (const float*)d_in[9];
    const float* dtb  = (const float*)d_in[10];
    const float* Alog = (const float*)d_in[11];
    const float* Dp   = (const float*)d_in[12];
    const float* opw  = (const float*)d_in[13];
    const float* opb  = (const float*)d_in[14];
    const float* nw   = (const float*)d_in[15];
    const float* nb   = (const float*)d_in[16];
    const float* clw  = (const float*)d_in[17];
    const float* clb  = (const float*)d_in[18];

    // f32-slot offsets (all non-overlapping):
    //   h        [0,        4194304)
    //   P        [4194304,  6291456)   (zb bf16 aliases P; dead before P used)
    //   Sb       [6291456,  8388608)
    //   xzb bf16 [8388608,  16777216)
    //   xcb bf16 [16777216, 20971520)
    //   projall  [20971520, 25690112)
    //   yb bf16  [25690112, 29884416)
    //   partial  [29884416, 29917184)
    //   wt1      [29917184, 30048256)  4*512*128 bf16 = 131,072 f32 slots
    //   wt2      [30048256, 30113792)  4*128*256 bf16 =  65,536 f32 slots
    //   wcat     [30113792, 30310400)  4*384*256 bf16 = 196,608 f32 slots
    float* ws = (float*)d_ws;
    float*  h       = ws;
    float*  P       = ws + 4194304;
    float*  Sb      = ws + 6291456;
    __bf16* zb      = (__bf16*)P;
    __bf16* xzb     = (__bf16*)(ws + 8388608);
    __bf16* xcb     = (__bf16*)(ws + 16777216);
    __bf16* projall = (__bf16*)(ws + 20971520);
    __bf16* yb      = (__bf16*)(ws + 25690112);
    float*  partial = ws + 29884416;
    __bf16* wt1     = (__bf16*)(ws + 29917184);
    __bf16* wt2     = (__bf16*)(ws + 30048256);
    __bf16* wcat    = (__bf16*)(ws + 30113792);

    k_prep_w<<<1024, 256, 0, stream>>>(ipw, opw, wt1, wt2);
    k_prep_wcat<<<4 * 384, 256, 0, stream>>>(xpw, dtw, wcat);
    k_embed<<<T_, 128, 0, stream>>>(x, Win, bin, h);
    for (int lay = 0; lay < 4; ++lay) {
        k_ln<<<T_ / 4, 256, 0, stream>>>(h, lnw + lay * 128, lnb + lay * 128, zb);
        k_gemm_mfma<64, 128, 512, 0, false><<<dim3(T_ / 64, 4), 256, 0, stream>>>(
            zb, nullptr, wt1 + (size_t)lay * 65536, nullptr, nullptr, xzb);
        k_conv<<<T_ / 4, 256, 0, stream>>>(xzb, cw + lay * 1024, cb + lay * 256, xcb);
        k_gemm_mfma<64, 256, 384, 1, false><<<dim3(T_ / 64, 3), 256, 0, stream>>>(
            xcb, nullptr, wcat + (size_t)lay * 98304, dtb + lay * 256, nullptr, projall);
        k_scan_chunk<false><<<dim3(4, NCH_, B_), 256, 0, stream>>>(projall, xcb,
            Alog + lay * 4096, Dp + lay * 256, P, Sb, yb);
        k_scan_combine<<<B_ * 4096 / 256, 256, 0, stream>>>(P, Sb);
        k_scan_chunk<true><<<dim3(4, NCH_, B_), 256, 0, stream>>>(projall, xcb,
            Alog + lay * 4096, Dp + lay * 256, P, Sb, yb);
        k_gemm_mfma<32, 256, 128, 2, true><<<dim3(T_ / 32, 1), 256, 0, stream>>>(
            yb, xzb, wt2 + (size_t)lay * 32768, opb + lay * 128, h, nullptr);
    }
    k_pool<<<dim3(32, 8), 128, 0, stream>>>(h, partial);
    k_head<<<32, 128, 0, stream>>>(partial, nw, nb, clw, clb, (float*)d_out);
}

// Round 10
// 651.091 us; speedup vs baseline: 5.3566x; 1.0201x over previous
//
#include <hip/hip_runtime.h>
#include <math.h>

// Problem constants
#define B_  32
#define L_  1024
#define T_  (B_ * L_)       // 32768 tokens
#define DM_ 128
#define DI_ 256
#define DS_ 16
#define DC_ 4
#define DR_ 8
#define NC_ 10
#define CHUNK_ 64
#define NCH_  (L_ / CHUNK_)   // 16 chunks
#define PSTR_ 288             // projall row stride (bf16): 256 delta | 32 B,C
#define PJS_  36              // projs LDS row stride (f32), 16B-aligned
#define DUS_  68              // du_lds row stride (u32), 16B-aligned

typedef __bf16 bf16x8 __attribute__((ext_vector_type(8)));
typedef __bf16 bf16x4 __attribute__((ext_vector_type(4)));
typedef __bf16 bf16x2 __attribute__((ext_vector_type(2)));
typedef float f32x4 __attribute__((ext_vector_type(4)));
typedef unsigned short u16x8 __attribute__((ext_vector_type(8)));

__device__ __forceinline__ float sigmoidf_(float x) { return 1.0f / (1.0f + __expf(-x)); }
__device__ __forceinline__ float siluf_(float x)    { return x * sigmoidf_(x); }
__device__ __forceinline__ float softplusf_(float x) {
    return (x > 15.0f) ? x : __logf(1.0f + __expf(x));
}
__device__ __forceinline__ float fexp2_(float x) { return __builtin_amdgcn_exp2f(x); }

// async 16B global->LDS (gfx950). dest = wave-uniform base + lane*16.
__device__ __forceinline__ void gload_lds16(const __bf16* g, __bf16* l) {
    __builtin_amdgcn_global_load_lds(
        (const __attribute__((address_space(1))) void*)g,
        (__attribute__((address_space(3))) void*)l, 16, 0, 0);
}

// Stage an R x 64 bf16 tile (row stride `stride`, col offset k0) into LDS with
// XOR-swizzle baked in: LDS (row, sw) holds source (row, sw ^ (row&7)).
template<int R>
__device__ __forceinline__ void stage_async(const __bf16* __restrict__ src,
        __bf16* lds, int k0, int stride, int wid, int lane) {
    constexpr int NI = R / 32;
#pragma unroll
    for (int j = 0; j < NI; ++j) {
        int s0 = (wid * NI + j) * 64;
        int s = s0 + lane;
        int row = s >> 3, sw = s & 7;
        int slot = sw ^ (row & 7);
        gload_lds16(src + (size_t)row * stride + k0 + slot * 8, lds + (size_t)s0 * 8);
    }
}

// ---------------- embed -----------------------------------------------------------
__global__ __launch_bounds__(128) void k_embed(const float* __restrict__ x,
        const float* __restrict__ Win, const float* __restrict__ bin,
        float* __restrict__ h) {
    int t = blockIdx.x;
    int b = t >> 10, l = t & 1023;
    int m = threadIdx.x;
    const float* xb = x + (size_t)b * 3 * 1024 + l;
    float acc = bin[m];
    acc = fmaf(xb[0],    Win[m],        acc);
    acc = fmaf(xb[1024], Win[128 + m],  acc);
    acc = fmaf(xb[2048], Win[256 + m],  acc);
    h[(size_t)t * 128 + m] = acc;
}

// ---------------- weight prep: transpose + bf16 convert ---------------------------
__global__ __launch_bounds__(256) void k_prep_w(const float* __restrict__ ipw,
        const float* __restrict__ opw, __bf16* __restrict__ wt1,
        __bf16* __restrict__ wt2) {
    int i = blockIdx.x * 256 + threadIdx.x;          // < 262144
    {
        int lay = i >> 16, rem = i & 65535, n = rem >> 7, k = rem & 127;
        wt1[i] = (__bf16)ipw[lay * 65536 + k * 512 + n];
    }
    if (i < 4 * 128 * 256) {
        int lay = i >> 15, rem = i & 32767, n = rem >> 8, k = rem & 255;
        wt2[i] = (__bf16)opw[lay * 32768 + k * 128 + n];
    }
}

// ---------------- Wcat prep: [lay][n<384][k<256] ----------------------------------
__global__ __launch_bounds__(256) void k_prep_wcat(const float* __restrict__ xpw,
        const float* __restrict__ dtw, __bf16* __restrict__ wcat) {
    int blk = blockIdx.x;              // lay*384 + n
    int lay = blk / 384, n = blk % 384;
    int k = threadIdx.x;
    float v;
    if (n < 256) {
        float acc = 0.0f;
#pragma unroll
        for (int r = 0; r < 8; ++r)
            acc = fmaf(xpw[lay * 10240 + k * 40 + r], dtw[lay * 2048 + r * 256 + n], acc);
        v = acc;
    } else if (n < 288) {
        v = xpw[lay * 10240 + k * 40 + (n - 248)];   // col 8 + (n-256)
    } else {
        v = 0.0f;
    }
    wcat[(size_t)blk * 256 + k] = (__bf16)v;
}

// ---------------- layernorm -> bf16 ----------------------------------------------
__global__ __launch_bounds__(256) void k_ln(const float* __restrict__ h,
        const float* __restrict__ w, const float* __restrict__ b,
        __bf16* __restrict__ z) {
    int wid = threadIdx.x >> 6, lane = threadIdx.x & 63;
    int t = blockIdx.x * 4 + wid;
    const float* hr = h + (size_t)t * 128;
    float2 v = *(const float2*)(hr + lane * 2);
    float s = v.x + v.y, sq = v.x * v.x + v.y * v.y;
#pragma unroll
    for (int off = 1; off < 64; off <<= 1) {
        s += __shfl_xor(s, off);
        sq += __shfl_xor(sq, off);
    }
    float mean = s * (1.0f / 128.0f);
    float var = sq * (1.0f / 128.0f) - mean * mean;
    float rstd = rsqrtf(var + 1e-5f);
    float2 wv = *(const float2*)(w + lane * 2);
    float2 bv = *(const float2*)(b + lane * 2);
    bf16x2 o;
    o.x = (__bf16)((v.x - mean) * rstd * wv.x + bv.x);
    o.y = (__bf16)((v.y - mean) * rstd * wv.y + bv.y);
    *(bf16x2*)(z + (size_t)t * 128 + lane * 2) = o;
}

// ---------------- bf16 MFMA GEMM, BM x 128 tile, BK=64 ---------------------------
template<int BM, int K, int N, int MODE, bool GATE>
__global__ __launch_bounds__(256) void k_gemm_mfma(
        const __bf16* __restrict__ A, const __bf16* __restrict__ G,
        const __bf16* __restrict__ Wt, const float* __restrict__ bias,
        float* __restrict__ Cf, __bf16* __restrict__ Cb) {
    static_assert(!GATE || BM == 32, "GATE staging assumes BM=32");
    __shared__ __bf16 As[BM * 64];
    __shared__ __bf16 Bs[128 * 64];
    int tid = threadIdx.x;
    int bm = blockIdx.x, bn = blockIdx.y;
    int lane = tid & 63, wid = tid >> 6;
    int lr = lane & 15, lg = lane >> 4;
    constexpr int MF = BM / 16;

    f32x4 acc[MF][2] = {};
    const __bf16* Asrc = A + (size_t)(bm * BM) * K;
    const __bf16* Bsrc = Wt + (size_t)(bn * 128) * K;

    for (int k0 = 0; k0 < K; k0 += 64) {
        if (GATE) {
            int row = tid >> 3, slot = tid & 7;
            int m = bm * BM + row;
            bf16x8 yv = *(const bf16x8*)(A + (size_t)m * K + k0 + slot * 8);
            bf16x8 gv = *(const bf16x8*)(G + (size_t)m * 512 + 256 + k0 + slot * 8);
            bf16x8 v;
#pragma unroll
            for (int j = 0; j < 8; ++j)
                v[j] = (__bf16)((float)yv[j] * siluf_((float)gv[j]));
            *(bf16x8*)(As + row * 64 + ((slot ^ (row & 7)) * 8)) = v;
        } else {
            stage_async<BM>(Asrc, As, k0, K, wid, lane);
        }
        stage_async<128>(Bsrc, Bs, k0, K, wid, lane);
        __syncthreads();
#pragma unroll
        for (int ks = 0; ks < 2; ++ks) {
            int slotbase = ks * 4 + lg;
            bf16x8 af[MF], bfr[2];
#pragma unroll
            for (int m = 0; m < MF; ++m) {
                int row = m * 16 + lr;
                af[m] = *(const bf16x8*)(As + row * 64 + ((slotbase ^ (row & 7)) * 8));
            }
#pragma unroll
            for (int n = 0; n < 2; ++n) {
                int rn = wid * 32 + n * 16 + lr;
                bfr[n] = *(const bf16x8*)(Bs + rn * 64 + ((slotbase ^ (rn & 7)) * 8));
            }
#pragma unroll
            for (int m = 0; m < MF; ++m)
#pragma unroll
                for (int n = 0; n < 2; ++n)
                    acc[m][n] = __builtin_amdgcn_mfma_f32_16x16x32_bf16(
                        af[m], bfr[n], acc[m][n], 0, 0, 0);
        }
        __syncthreads();
    }
#pragma unroll
    for (int m = 0; m < MF; ++m) {
#pragma unroll
        for (int n = 0; n < 2; ++n) {
            int col = bn * 128 + wid * 32 + n * 16 + lr;
            float bv = (MODE == 2) ? bias[col] : 0.0f;
            float dtbv = (MODE == 1 && col < 256) ? bias[col] : 0.0f;
#pragma unroll
            for (int rg = 0; rg < 4; ++rg) {
                int row = bm * BM + m * 16 + lg * 4 + rg;
                float v = acc[m][n][rg];
                if (MODE == 0) {
                    Cb[(size_t)row * N + col] = (__bf16)v;
                } else if (MODE == 1) {
                    if (col < 256)
                        Cb[(size_t)row * PSTR_ + col] = (__bf16)softplusf_(v + dtbv);
                    else if (col < 288)
                        Cb[(size_t)row * PSTR_ + col] = (__bf16)v;
                } else {
                    float* cp = Cf + (size_t)row * N + col;
                    *cp = *cp + v + bv;
                }
            }
        }
    }
}

// ---------------- causal depthwise conv (width 4) + SiLU, vectorized -------------
__global__ __launch_bounds__(256) void k_conv(const __bf16* __restrict__ xzb,
        const float* __restrict__ cw, const float* __restrict__ cb,
        __bf16* __restrict__ xcb) {
    int t = blockIdx.x * 4 + (threadIdx.x >> 6);
    int d0 = (threadIdx.x & 63) * 4;
    int l = t & 1023;
    const __bf16* xp = xzb + (size_t)t * 512 + d0;
    float4 wv[4];
#pragma unroll
    for (int j = 0; j < 4; ++j) wv[j] = *(const float4*)(cw + (d0 + j) * 4);
    float acc[4] = {cb[d0], cb[d0 + 1], cb[d0 + 2], cb[d0 + 3]};
#pragma unroll
    for (int k = 0; k < 4; ++k) {
        int back = 3 - k;
        if (l >= back) {
            bf16x4 v = *(const bf16x4*)(xp - back * 512);
#pragma unroll
            for (int j = 0; j < 4; ++j)
                acc[j] = fmaf((float)v[j], ((const float*)&wv[j])[k], acc[j]);
        }
    }
    bf16x4 o;
#pragma unroll
    for (int j = 0; j < 4; ++j) o[j] = (__bf16)siluf_(acc[j]);
    *(bf16x4*)(xcb + (size_t)t * 256 + d0) = o;
}

// ---------------- chunk-parallel SSM scan (vectorized LDS) -----------------------
// projall[t][0..255]=delta(d), [256..271]=B, [272..287]=C (bf16, stride PSTR_).
// LDS: projs[t][0..15]=B,[16..31]=C (f32, stride 36);
//      du_lds[t][dl] = u32 with delta bits in low16, u bits in high16 (stride 68).
template<bool FINAL>
__global__ __launch_bounds__(256) void k_scan_chunk(
        const __bf16* __restrict__ projall, const __bf16* __restrict__ xcb,
        const float* __restrict__ Alog, const float* __restrict__ Dp,
        float* __restrict__ P, float* __restrict__ S,
        __bf16* __restrict__ yb) {
    __shared__ float projs[CHUNK_ * PJS_];       // 9216 B
    __shared__ unsigned du_lds[CHUNK_ * DUS_];   // 17408 B
    int b = blockIdx.z, c = blockIdx.y, dg = blockIdx.x;
    int tid = threadIdx.x;
    int dl = tid >> 2;
    int d = dg * 64 + dl;
    int q = tid & 3;

    const __bf16* projC = projall + ((size_t)b * 1024 + c * CHUNK_) * PSTR_;
    const __bf16* xcC   = xcb + ((size_t)b * 1024 + c * CHUNK_) * 256 + dg * 64;

    // ---- stage chunk operands ----
    {
        int t = tid >> 2, g4 = tid & 3;
        // B|C -> f32 (two float4 writes, 16B-aligned: 36*4=144 = 9*16)
        bf16x8 v = *(const bf16x8*)(projC + (size_t)t * PSTR_ + 256 + g4 * 8);
        float4 f0 = {(float)v[0], (float)v[1], (float)v[2], (float)v[3]};
        float4 f1 = {(float)v[4], (float)v[5], (float)v[6], (float)v[7]};
        *(float4*)(projs + t * PJS_ + g4 * 8)     = f0;
        *(float4*)(projs + t * PJS_ + g4 * 8 + 4) = f1;
        // delta | u interleave: 16 values per thread (s0..s0+15)
        int s0 = g4 * 16;
        u16x8 d0 = *(const u16x8*)(projC + (size_t)t * PSTR_ + dg * 64 + s0);
        u16x8 d1 = *(const u16x8*)(projC + (size_t)t * PSTR_ + dg * 64 + s0 + 8);
        u16x8 x0 = *(const u16x8*)(xcC + (size_t)t * 256 + s0);
        u16x8 x1 = *(const u16x8*)(xcC + (size_t)t * 256 + s0 + 8);
        uint4 w0, w1, w2, w3;
        w0.x = d0[0] | ((unsigned)x0[0] << 16); w0.y = d0[1] | ((unsigned)x0[1] << 16);
        w0.z = d0[2] | ((unsigned)x0[2] << 16); w0.w = d0[3] | ((unsigned)x0[3] << 16);
        w1.x = d0[4] | ((unsigned)x0[4] << 16); w1.y = d0[5] | ((unsigned)x0[5] << 16);
        w1.z = d0[6] | ((unsigned)x0[6] << 16); w1.w = d0[7] | ((unsigned)x0[7] << 16);
        w2.x = d1[0] | ((unsigned)x1[0] << 16); w2.y = d1[1] | ((unsigned)x1[1] << 16);
        w2.z = d1[2] | ((unsigned)x1[2] << 16); w2.w = d1[3] | ((unsigned)x1[3] << 16);
        w3.x = d1[4] | ((unsigned)x1[4] << 16); w3.y = d1[5] | ((unsigned)x1[5] << 16);
        w3.z = d1[6] | ((unsigned)x1[6] << 16); w3.w = d1[7] | ((unsigned)x1[7] << 16);
        unsigned* dst = du_lds + t * DUS_ + s0;   // (t*68+s0)*4 B, 16B-aligned
        *(uint4*)(dst)      = w0;
        *(uint4*)(dst + 4)  = w1;
        *(uint4*)(dst + 8)  = w2;
        *(uint4*)(dst + 12) = w3;
    }

    float aa[4];
#pragma unroll
    for (int j = 0; j < 4; ++j)
        aa[j] = -__expf(Alog[d * 16 + q * 4 + j]) * 1.44269504088896f;
    float Dpd = Dp[d];

    size_t psIdx = ((size_t)(b * NCH_ + c)) * 4096 + d * 16 + q * 4;
    float hs[4] = {0.0f, 0.0f, 0.0f, 0.0f};
    if (FINAL) {
        float4 h0 = *(const float4*)(P + psIdx);
        hs[0] = h0.x; hs[1] = h0.y; hs[2] = h0.z; hs[3] = h0.w;
    }
    float cumd = 0.0f;

    __bf16* yC = yb + ((size_t)b * 1024 + c * CHUNK_) * 256 + dg * 64;

    __syncthreads();
    for (int tt = 0; tt < CHUNK_; ++tt) {
        unsigned duv = du_lds[tt * DUS_ + dl];
        float delta_t = __uint_as_float(duv << 16);
        float u = __uint_as_float(duv & 0xffff0000u);
        float4 Bv = *(const float4*)(projs + tt * PJS_ + q * 4);
        float du = delta_t * u;
        if (!FINAL) cumd += delta_t;
        float ys = 0.0f;
        if (FINAL) {
            float4 Cv = *(const float4*)(projs + tt * PJS_ + 16 + q * 4);
#pragma unroll
            for (int j = 0; j < 4; ++j) {
                float dA = fexp2_(delta_t * aa[j]);
                hs[j] = fmaf(dA, hs[j], du * ((const float*)&Bv)[j]);
                ys = fmaf(hs[j], ((const float*)&Cv)[j], ys);
            }
            ys += __shfl_xor(ys, 1);
            ys += __shfl_xor(ys, 2);
            if (q == 0) {
                float yv = fmaf(u, Dpd, ys);
                yv = fmaf(0.7f, yv, 0.3f * u);
                yC[(size_t)tt * 256 + dl] = (__bf16)yv;
            }
        } else {
#pragma unroll
            for (int j = 0; j < 4; ++j) {
                float dA = fexp2_(delta_t * aa[j]);
                hs[j] = fmaf(dA, hs[j], du * ((const float*)&Bv)[j]);
            }
        }
    }
    if (!FINAL) {
        float4 pv, sv;
        pv.x = fexp2_(aa[0] * cumd); pv.y = fexp2_(aa[1] * cumd);
        pv.z = fexp2_(aa[2] * cumd); pv.w = fexp2_(aa[3] * cumd);
        sv.x = hs[0]; sv.y = hs[1]; sv.z = hs[2]; sv.w = hs[3];
        *(float4*)(P + psIdx) = pv;
        *(float4*)(S + psIdx) = sv;
    }
}

// ---------------- combine chunk aggregates ---------------------------------------
__global__ __launch_bounds__(256) void k_scan_combine(float* __restrict__ P,
        const float* __restrict__ S) {
    int idx = blockIdx.x * 256 + threadIdx.x;
    int b = idx >> 12, rem = idx & 4095;
    float h = 0.0f;
#pragma unroll
    for (int c = 0; c < NCH_; ++c) {
        size_t base = ((size_t)(b * NCH_ + c)) * 4096 + rem;
        float p = P[base];
        float s = S[base];
        P[base] = h;
        h = fmaf(p, h, s);
    }
}

// ---------------- mean-pool over L: deterministic two-stage ----------------------
__global__ __launch_bounds__(128) void k_pool(const float* __restrict__ h,
        float* __restrict__ partial) {
    int b = blockIdx.x, lc = blockIdx.y;
    int m = threadIdx.x;
    const float* hb = h + (size_t)b * 131072 + (size_t)lc * 128 * 128 + m;
    float acc = 0.0f;
#pragma unroll 8
    for (int l = 0; l < 128; ++l) acc += hb[(size_t)l * 128];
    partial[((size_t)b * 8 + lc) * 128 + m] = acc;
}

// ---------------- final LN + classifier (sums 8 partials) ------------------------
__global__ __launch_bounds__(128) void k_head(const float* __restrict__ partial,
        const float* __restrict__ nw, const float* __restrict__ nb,
        const float* __restrict__ cw, const float* __restrict__ cb,
        float* __restrict__ out) {
    __shared__ float zs[128];
    __shared__ float red[128];
    int b = blockIdx.x, m = threadIdx.x;
    float v = 0.0f;
#pragma unroll
    for (int lc = 0; lc < 8; ++lc) v += partial[((size_t)b * 8 + lc) * 128 + m];
    v *= (1.0f / 1024.0f);
    red[m] = v;
    __syncthreads();
    for (int off = 64; off; off >>= 1) {
        if (m < off) red[m] += red[m + off];
        __syncthreads();
    }
    float mean = red[0] * (1.0f / 128.0f);
    __syncthreads();
    float dv = v - mean;
    red[m] = dv * dv;
    __syncthreads();
    for (int off = 64; off; off >>= 1) {
        if (m < off) red[m] += red[m + off];
        __syncthreads();
    }
    float rstd = rsqrtf(red[0] * (1.0f / 128.0f) + 1e-5f);
    zs[m] = dv * rstd * nw[m] + nb[m];
    __syncthreads();
    if (m < NC_) {
        float acc = cb[m];
#pragma unroll 8
        for (int k = 0; k < 128; ++k) acc = fmaf(zs[k], cw[k * 10 + m], acc);
        out[b * 10 + m] = acc;
    }
}

extern "C" void kernel_launch(void* const* d_in, const int* in_sizes, int n_in,
                              void* d_out, int out_size, void* d_ws, size_t ws_size,
                              hipStream_t stream) {
    const float* x    = (const float*)d_in[0];
    const float* Win  = (const float*)d_in[1];
    const float* bin  = (const float*)d_in[2];
    const float* lnw  = (const float*)d_in[3];
    const float* lnb  = (const float*)d_in[4];
    const float* ipw  = (const float*)d_in[5];
    const float* cw   = (const float*)d_in[6];
    const float* cb   = (const float*)d_in[7];
    const float* xpw  = (const float*)d_in[8];
    const float* dtw  = (const float*)d_in[9];
    const float* dtb  = (const float*)d_in[10];
    const float* Alog = (const float*)d_in[11];
    const float* Dp   = (const float*)d_in[12];
    const float* opw  = (const float*)d_in[13];
    const float* opb  = (const float*)d_in[14];
    const float* nw   = (const float*)d_in[15];
    const float* nb   = (const float*)d_in[16];
    const float* clw  = (const float*)d_in[17];
    const float* clb  = (const float*)d_in[18];

    // f32-slot offsets (all non-overlapping):
    //   h        [0,        4194304)
    //   P        [4194304,  6291456)   (zb bf16 aliases P; dead before P used)
    //   Sb       [6291456,  8388608)
    //   xzb bf16 [8388608,  16777216)
    //   xcb bf16 [16777216, 20971520)
    //   projall  [20971520, 25690112)
    //   yb bf16  [25690112, 29884416)
    //   partial  [29884416, 29917184)
    //   wt1      [29917184, 30048256)
    //   wt2      [30048256, 30113792)
    //   wcat     [30113792, 30310400)
    float* ws = (float*)d_ws;
    float*  h       = ws;
    float*  P       = ws + 4194304;
    float*  Sb      = ws + 6291456;
    __bf16* zb      = (__bf16*)P;
    __bf16* xzb     = (__bf16*)(ws + 8388608);
    __bf16* xcb     = (__bf16*)(ws + 16777216);
    __bf16* projall = (__bf16*)(ws + 20971520);
    __bf16* yb      = (__bf16*)(ws + 25690112);
    float*  partial = ws + 29884416;
    __bf16* wt1     = (__bf16*)(ws + 29917184);
    __bf16* wt2     = (__bf16*)(ws + 30048256);
    __bf16* wcat    = (__bf16*)(ws + 30113792);

    k_prep_w<<<1024, 256, 0, stream>>>(ipw, opw, wt1, wt2);
    k_prep_wcat<<<4 * 384, 256, 0, stream>>>(xpw, dtw, wcat);
    k_embed<<<T_, 128, 0, stream>>>(x, Win, bin, h);
    for (int lay = 0; lay < 4; ++lay) {
        k_ln<<<T_ / 4, 256, 0, stream>>>(h, lnw + lay * 128, lnb + lay * 128, zb);
        k_gemm_mfma<64, 128, 512, 0, false><<<dim3(T_ / 64, 4), 256, 0, stream>>>(
            zb, nullptr, wt1 + (size_t)lay * 65536, nullptr, nullptr, xzb);
        k_conv<<<T_ / 4, 256, 0, stream>>>(xzb, cw + lay * 1024, cb + lay * 256, xcb);
        k_gemm_mfma<64, 256, 384, 1, false><<<dim3(T_ / 64, 3), 256, 0, stream>>>(
            xcb, nullptr, wcat + (size_t)lay * 98304, dtb + lay * 256, nullptr, projall);
        k_scan_chunk<false><<<dim3(4, NCH_, B_), 256, 0, stream>>>(projall, xcb,
            Alog + lay * 4096, Dp + lay * 256, P, Sb, yb);
        k_scan_combine<<<B_ * 4096 / 256, 256, 0, stream>>>(P, Sb);
        k_scan_chunk<true><<<dim3(4, NCH_, B_), 256, 0, stream>>>(projall, xcb,
            Alog + lay * 4096, Dp + lay * 256, P, Sb, yb);
        k_gemm_mfma<32, 256, 128, 2, true><<<dim3(T_ / 32, 1), 256, 0, stream>>>(
            yb, xzb, wt2 + (size_t)lay * 32768, opb + lay * 128, h, nullptr);
    }
    k_pool<<<dim3(32, 8), 128, 0, stream>>>(h, partial);
    k_head<<<32, 128, 0, stream>>>(partial, nw, nb, clw, clb, (float*)d_out);
}

// Round 11
// 639.565 us; speedup vs baseline: 5.4531x; 1.0180x over previous
//
#include <hip/hip_runtime.h>
#include <math.h>

// Problem constants
#define B_  32
#define L_  1024
#define T_  (B_ * L_)       // 32768 tokens
#define DM_ 128
#define DI_ 256
#define DS_ 16
#define DC_ 4
#define DR_ 8
#define NC_ 10
#define CHUNK_ 64
#define NCH_  (L_ / CHUNK_)   // 16 chunks
#define PSTR_ 288             // projall row stride (bf16): 256 delta | 32 B,C

typedef __bf16 bf16x8 __attribute__((ext_vector_type(8)));
typedef __bf16 bf16x4 __attribute__((ext_vector_type(4)));
typedef __bf16 bf16x2 __attribute__((ext_vector_type(2)));
typedef float f32x4 __attribute__((ext_vector_type(4)));
typedef unsigned short u16x8 __attribute__((ext_vector_type(8)));

__device__ __forceinline__ float sigmoidf_(float x) { return 1.0f / (1.0f + __expf(-x)); }
__device__ __forceinline__ float siluf_(float x)    { return x * sigmoidf_(x); }
__device__ __forceinline__ float softplusf_(float x) {
    return (x > 15.0f) ? x : __logf(1.0f + __expf(x));
}
__device__ __forceinline__ float fexp2_(float x) { return __builtin_amdgcn_exp2f(x); }

// async 16B global->LDS (gfx950). dest = wave-uniform base + lane*16.
__device__ __forceinline__ void gload_lds16(const __bf16* g, __bf16* l) {
    __builtin_amdgcn_global_load_lds(
        (const __attribute__((address_space(1))) void*)g,
        (__attribute__((address_space(3))) void*)l, 16, 0, 0);
}

// Stage an R x 64 bf16 tile (row stride `stride`, col offset k0) into LDS with
// XOR-swizzle baked in: LDS (row, sw) holds source (row, sw ^ (row&7)).
template<int R>
__device__ __forceinline__ void stage_async(const __bf16* __restrict__ src,
        __bf16* lds, int k0, int stride, int wid, int lane) {
    constexpr int NI = R / 32;
#pragma unroll
    for (int j = 0; j < NI; ++j) {
        int s0 = (wid * NI + j) * 64;
        int s = s0 + lane;
        int row = s >> 3, sw = s & 7;
        int slot = sw ^ (row & 7);
        gload_lds16(src + (size_t)row * stride + k0 + slot * 8, lds + (size_t)s0 * 8);
    }
}

// ---------------- embed -----------------------------------------------------------
__global__ __launch_bounds__(128) void k_embed(const float* __restrict__ x,
        const float* __restrict__ Win, const float* __restrict__ bin,
        float* __restrict__ h) {
    int t = blockIdx.x;
    int b = t >> 10, l = t & 1023;
    int m = threadIdx.x;
    const float* xb = x + (size_t)b * 3 * 1024 + l;
    float acc = bin[m];
    acc = fmaf(xb[0],    Win[m],        acc);
    acc = fmaf(xb[1024], Win[128 + m],  acc);
    acc = fmaf(xb[2048], Win[256 + m],  acc);
    h[(size_t)t * 128 + m] = acc;
}

// ---------------- weight prep: transpose + bf16 convert ---------------------------
__global__ __launch_bounds__(256) void k_prep_w(const float* __restrict__ ipw,
        const float* __restrict__ opw, __bf16* __restrict__ wt1,
        __bf16* __restrict__ wt2) {
    int i = blockIdx.x * 256 + threadIdx.x;          // < 262144
    {
        int lay = i >> 16, rem = i & 65535, n = rem >> 7, k = rem & 127;
        wt1[i] = (__bf16)ipw[lay * 65536 + k * 512 + n];
    }
    if (i < 4 * 128 * 256) {
        int lay = i >> 15, rem = i & 32767, n = rem >> 8, k = rem & 255;
        wt2[i] = (__bf16)opw[lay * 32768 + k * 128 + n];
    }
}

// ---------------- Wcat prep: [lay][n<384][k<256] ----------------------------------
__global__ __launch_bounds__(256) void k_prep_wcat(const float* __restrict__ xpw,
        const float* __restrict__ dtw, __bf16* __restrict__ wcat) {
    int blk = blockIdx.x;              // lay*384 + n
    int lay = blk / 384, n = blk % 384;
    int k = threadIdx.x;
    float v;
    if (n < 256) {
        float acc = 0.0f;
#pragma unroll
        for (int r = 0; r < 8; ++r)
            acc = fmaf(xpw[lay * 10240 + k * 40 + r], dtw[lay * 2048 + r * 256 + n], acc);
        v = acc;
    } else if (n < 288) {
        v = xpw[lay * 10240 + k * 40 + (n - 248)];   // col 8 + (n-256)
    } else {
        v = 0.0f;
    }
    wcat[(size_t)blk * 256 + k] = (__bf16)v;
}

// ---------------- layernorm -> bf16 ----------------------------------------------
__global__ __launch_bounds__(256) void k_ln(const float* __restrict__ h,
        const float* __restrict__ w, const float* __restrict__ b,
        __bf16* __restrict__ z) {
    int wid = threadIdx.x >> 6, lane = threadIdx.x & 63;
    int t = blockIdx.x * 4 + wid;
    const float* hr = h + (size_t)t * 128;
    float2 v = *(const float2*)(hr + lane * 2);
    float s = v.x + v.y, sq = v.x * v.x + v.y * v.y;
#pragma unroll
    for (int off = 1; off < 64; off <<= 1) {
        s += __shfl_xor(s, off);
        sq += __shfl_xor(sq, off);
    }
    float mean = s * (1.0f / 128.0f);
    float var = sq * (1.0f / 128.0f) - mean * mean;
    float rstd = rsqrtf(var + 1e-5f);
    float2 wv = *(const float2*)(w + lane * 2);
    float2 bv = *(const float2*)(b + lane * 2);
    bf16x2 o;
    o.x = (__bf16)((v.x - mean) * rstd * wv.x + bv.x);
    o.y = (__bf16)((v.y - mean) * rstd * wv.y + bv.y);
    *(bf16x2*)(z + (size_t)t * 128 + lane * 2) = o;
}

// ---------------- bf16 MFMA GEMM, BM x 128 tile, BK=64 ---------------------------
template<int BM, int K, int N, int MODE, bool GATE>
__global__ __launch_bounds__(256) void k_gemm_mfma(
        const __bf16* __restrict__ A, const __bf16* __restrict__ G,
        const __bf16* __restrict__ Wt, const float* __restrict__ bias,
        float* __restrict__ Cf, __bf16* __restrict__ Cb) {
    static_assert(!GATE || BM == 32, "GATE staging assumes BM=32");
    __shared__ __bf16 As[BM * 64];
    __shared__ __bf16 Bs[128 * 64];
    int tid = threadIdx.x;
    int bm = blockIdx.x, bn = blockIdx.y;
    int lane = tid & 63, wid = tid >> 6;
    int lr = lane & 15, lg = lane >> 4;
    constexpr int MF = BM / 16;

    f32x4 acc[MF][2] = {};
    const __bf16* Asrc = A + (size_t)(bm * BM) * K;
    const __bf16* Bsrc = Wt + (size_t)(bn * 128) * K;

    for (int k0 = 0; k0 < K; k0 += 64) {
        if (GATE) {
            int row = tid >> 3, slot = tid & 7;
            int m = bm * BM + row;
            bf16x8 yv = *(const bf16x8*)(A + (size_t)m * K + k0 + slot * 8);
            bf16x8 gv = *(const bf16x8*)(G + (size_t)m * 512 + 256 + k0 + slot * 8);
            bf16x8 v;
#pragma unroll
            for (int j = 0; j < 8; ++j)
                v[j] = (__bf16)((float)yv[j] * siluf_((float)gv[j]));
            *(bf16x8*)(As + row * 64 + ((slot ^ (row & 7)) * 8)) = v;
        } else {
            stage_async<BM>(Asrc, As, k0, K, wid, lane);
        }
        stage_async<128>(Bsrc, Bs, k0, K, wid, lane);
        __syncthreads();
#pragma unroll
        for (int ks = 0; ks < 2; ++ks) {
            int slotbase = ks * 4 + lg;
            bf16x8 af[MF], bfr[2];
#pragma unroll
            for (int m = 0; m < MF; ++m) {
                int row = m * 16 + lr;
                af[m] = *(const bf16x8*)(As + row * 64 + ((slotbase ^ (row & 7)) * 8));
            }
#pragma unroll
            for (int n = 0; n < 2; ++n) {
                int rn = wid * 32 + n * 16 + lr;
                bfr[n] = *(const bf16x8*)(Bs + rn * 64 + ((slotbase ^ (rn & 7)) * 8));
            }
#pragma unroll
            for (int m = 0; m < MF; ++m)
#pragma unroll
                for (int n = 0; n < 2; ++n)
                    acc[m][n] = __builtin_amdgcn_mfma_f32_16x16x32_bf16(
                        af[m], bfr[n], acc[m][n], 0, 0, 0);
        }
        __syncthreads();
    }
#pragma unroll
    for (int m = 0; m < MF; ++m) {
#pragma unroll
        for (int n = 0; n < 2; ++n) {
            int col = bn * 128 + wid * 32 + n * 16 + lr;
            float bv = (MODE == 2) ? bias[col] : 0.0f;
            float dtbv = (MODE == 1 && col < 256) ? bias[col] : 0.0f;
#pragma unroll
            for (int rg = 0; rg < 4; ++rg) {
                int row = bm * BM + m * 16 + lg * 4 + rg;
                float v = acc[m][n][rg];
                if (MODE == 0) {
                    Cb[(size_t)row * N + col] = (__bf16)v;
                } else if (MODE == 1) {
                    if (col < 256)
                        Cb[(size_t)row * PSTR_ + col] = (__bf16)softplusf_(v + dtbv);
                    else if (col < 288)
                        Cb[(size_t)row * PSTR_ + col] = (__bf16)v;
                } else {
                    float* cp = Cf + (size_t)row * N + col;
                    *cp = *cp + v + bv;
                }
            }
        }
    }
}

// ---------------- causal depthwise conv (width 4) + SiLU, vectorized -------------
__global__ __launch_bounds__(256) void k_conv(const __bf16* __restrict__ xzb,
        const float* __restrict__ cw, const float* __restrict__ cb,
        __bf16* __restrict__ xcb) {
    int t = blockIdx.x * 4 + (threadIdx.x >> 6);
    int d0 = (threadIdx.x & 63) * 4;
    int l = t & 1023;
    const __bf16* xp = xzb + (size_t)t * 512 + d0;
    float4 wv[4];
#pragma unroll
    for (int j = 0; j < 4; ++j) wv[j] = *(const float4*)(cw + (d0 + j) * 4);
    float acc[4] = {cb[d0], cb[d0 + 1], cb[d0 + 2], cb[d0 + 3]};
#pragma unroll
    for (int k = 0; k < 4; ++k) {
        int back = 3 - k;
        if (l >= back) {
            bf16x4 v = *(const bf16x4*)(xp - back * 512);
#pragma unroll
            for (int j = 0; j < 4; ++j)
                acc[j] = fmaf((float)v[j], ((const float*)&wv[j])[k], acc[j]);
        }
    }
    bf16x4 o;
#pragma unroll
    for (int j = 0; j < 4; ++j) o[j] = (__bf16)siluf_(acc[j]);
    *(bf16x4*)(xcb + (size_t)t * 256 + d0) = o;
}

// ---------------- chunk-parallel SSM scan: one thread per d ----------------------
// projall[t][0..255]=delta(d), [256..271]=B, [272..287]=C (bf16, stride PSTR_).
// Block: 128 threads (d = dg*128 + tid), grid (2, NCH_, B_).
// LDS: du_lds[t][dl] = delta bits lo16 | u bits hi16 (32 KB); bc[t][0..31] (8 KB).
// Each thread keeps all 16 states in registers; no cross-lane ops.
template<bool FINAL>
__global__ __launch_bounds__(128) void k_scan_chunk(
        const __bf16* __restrict__ projall, const __bf16* __restrict__ xcb,
        const float* __restrict__ Alog, const float* __restrict__ Dp,
        float* __restrict__ P, float* __restrict__ S,
        __bf16* __restrict__ yb) {
    __shared__ unsigned du_lds[CHUNK_ * 128];   // 32 KB
    __shared__ float bc[CHUNK_ * 32];           // 8 KB
    int b = blockIdx.z, c = blockIdx.y, dg = blockIdx.x;   // dg in {0,1}
    int tid = threadIdx.x;                      // 0..127
    int d = dg * 128 + tid;

    const __bf16* projC = projall + ((size_t)b * 1024 + c * CHUNK_) * PSTR_;
    const __bf16* xcC   = xcb + ((size_t)b * 1024 + c * CHUNK_) * 256 + dg * 128;

    // ---- stage delta|u interleaved: 64t x 128d, 8-d granules, 8 per thread ----
#pragma unroll
    for (int r = 0; r < 8; ++r) {
        int item = r * 128 + tid;               // 0..1023
        int t = item >> 4, o8 = (item & 15) * 8;
        u16x8 dv = *(const u16x8*)(projC + (size_t)t * PSTR_ + dg * 128 + o8);
        u16x8 xv = *(const u16x8*)(xcC + (size_t)t * 256 + o8);
        uint4 w0, w1;
        w0.x = dv[0] | ((unsigned)xv[0] << 16); w0.y = dv[1] | ((unsigned)xv[1] << 16);
        w0.z = dv[2] | ((unsigned)xv[2] << 16); w0.w = dv[3] | ((unsigned)xv[3] << 16);
        w1.x = dv[4] | ((unsigned)xv[4] << 16); w1.y = dv[5] | ((unsigned)xv[5] << 16);
        w1.z = dv[6] | ((unsigned)xv[6] << 16); w1.w = dv[7] | ((unsigned)xv[7] << 16);
        *(uint4*)(du_lds + t * 128 + o8)     = w0;
        *(uint4*)(du_lds + t * 128 + o8 + 4) = w1;
    }
    // ---- stage B|C as f32: 64t x 32, 8-val granules, 2 per thread ----
#pragma unroll
    for (int r = 0; r < 2; ++r) {
        int item = r * 128 + tid;               // 0..255
        int t = item >> 2, g8 = (item & 3) * 8;
        bf16x8 v = *(const bf16x8*)(projC + (size_t)t * PSTR_ + 256 + g8);
        float4 f0 = {(float)v[0], (float)v[1], (float)v[2], (float)v[3]};
        float4 f1 = {(float)v[4], (float)v[5], (float)v[6], (float)v[7]};
        *(float4*)(bc + t * 32 + g8)     = f0;
        *(float4*)(bc + t * 32 + g8 + 4) = f1;
    }

    // ---- per-thread constants: all 16 states ----
    float aa[16], hs[16];
#pragma unroll
    for (int jj = 0; jj < 4; ++jj) {
        float4 av = *(const float4*)(Alog + (size_t)d * 16 + jj * 4);
        aa[jj * 4 + 0] = -__expf(av.x) * 1.44269504088896f;
        aa[jj * 4 + 1] = -__expf(av.y) * 1.44269504088896f;
        aa[jj * 4 + 2] = -__expf(av.z) * 1.44269504088896f;
        aa[jj * 4 + 3] = -__expf(av.w) * 1.44269504088896f;
    }
    float Dpd = Dp[d];
    size_t psIdx = ((size_t)(b * NCH_ + c)) * 4096 + (size_t)d * 16;
    if (FINAL) {
#pragma unroll
        for (int jj = 0; jj < 4; ++jj) {
            float4 h0 = *(const float4*)(P + psIdx + jj * 4);
            hs[jj * 4 + 0] = h0.x; hs[jj * 4 + 1] = h0.y;
            hs[jj * 4 + 2] = h0.z; hs[jj * 4 + 3] = h0.w;
        }
    } else {
#pragma unroll
        for (int j = 0; j < 16; ++j) hs[j] = 0.0f;
    }
    float cumd = 0.0f;
    __bf16* yC = yb + ((size_t)b * 1024 + c * CHUNK_) * 256 + dg * 128 + tid;

    __syncthreads();
#pragma unroll 2
    for (int tt = 0; tt < CHUNK_; ++tt) {
        unsigned duv = du_lds[tt * 128 + tid];
        float delta_t = __uint_as_float(duv << 16);
        float u = __uint_as_float(duv & 0xffff0000u);
        float du = delta_t * u;
        const float* bcr = bc + tt * 32;
        if (!FINAL) cumd += delta_t;
        float ys = 0.0f;
#pragma unroll
        for (int jj = 0; jj < 4; ++jj) {
            float4 Bv = *(const float4*)(bcr + jj * 4);
            float4 Cv;
            if (FINAL) Cv = *(const float4*)(bcr + 16 + jj * 4);
#pragma unroll
            for (int j = 0; j < 4; ++j) {
                int s = jj * 4 + j;
                float dA = fexp2_(delta_t * aa[s]);
                hs[s] = fmaf(dA, hs[s], du * ((const float*)&Bv)[j]);
                if (FINAL) ys = fmaf(hs[s], ((const float*)&Cv)[j], ys);
            }
        }
        if (FINAL) {
            float yv = fmaf(u, Dpd, ys);
            yv = fmaf(0.7f, yv, 0.3f * u);
            yC[(size_t)tt * 256] = (__bf16)yv;
        }
    }
    if (!FINAL) {
#pragma unroll
        for (int jj = 0; jj < 4; ++jj) {
            float4 pv, sv;
            pv.x = fexp2_(aa[jj * 4 + 0] * cumd);
            pv.y = fexp2_(aa[jj * 4 + 1] * cumd);
            pv.z = fexp2_(aa[jj * 4 + 2] * cumd);
            pv.w = fexp2_(aa[jj * 4 + 3] * cumd);
            sv.x = hs[jj * 4 + 0]; sv.y = hs[jj * 4 + 1];
            sv.z = hs[jj * 4 + 2]; sv.w = hs[jj * 4 + 3];
            *(float4*)(P + psIdx + jj * 4) = pv;
            *(float4*)(S + psIdx + jj * 4) = sv;
        }
    }
}

// ---------------- combine chunk aggregates ---------------------------------------
__global__ __launch_bounds__(256) void k_scan_combine(float* __restrict__ P,
        const float* __restrict__ S) {
    int idx = blockIdx.x * 256 + threadIdx.x;
    int b = idx >> 12, rem = idx & 4095;
    float h = 0.0f;
#pragma unroll
    for (int c = 0; c < NCH_; ++c) {
        size_t base = ((size_t)(b * NCH_ + c)) * 4096 + rem;
        float p = P[base];
        float s = S[base];
        P[base] = h;
        h = fmaf(p, h, s);
    }
}

// ---------------- mean-pool over L: deterministic two-stage ----------------------
__global__ __launch_bounds__(128) void k_pool(const float* __restrict__ h,
        float* __restrict__ partial) {
    int b = blockIdx.x, lc = blockIdx.y;
    int m = threadIdx.x;
    const float* hb = h + (size_t)b * 131072 + (size_t)lc * 128 * 128 + m;
    float acc = 0.0f;
#pragma unroll 8
    for (int l = 0; l < 128; ++l) acc += hb[(size_t)l * 128];
    partial[((size_t)b * 8 + lc) * 128 + m] = acc;
}

// ---------------- final LN + classifier (sums 8 partials) ------------------------
__global__ __launch_bounds__(128) void k_head(const float* __restrict__ partial,
        const float* __restrict__ nw, const float* __restrict__ nb,
        const float* __restrict__ cw, const float* __restrict__ cb,
        float* __restrict__ out) {
    __shared__ float zs[128];
    __shared__ float red[128];
    int b = blockIdx.x, m = threadIdx.x;
    float v = 0.0f;
#pragma unroll
    for (int lc = 0; lc < 8; ++lc) v += partial[((size_t)b * 8 + lc) * 128 + m];
    v *= (1.0f / 1024.0f);
    red[m] = v;
    __syncthreads();
    for (int off = 64; off; off >>= 1) {
        if (m < off) red[m] += red[m + off];
        __syncthreads();
    }
    float mean = red[0] * (1.0f / 128.0f);
    __syncthreads();
    float dv = v - mean;
    red[m] = dv * dv;
    __syncthreads();
    for (int off = 64; off; off >>= 1) {
        if (m < off) red[m] += red[m + off];
        __syncthreads();
    }
    float rstd = rsqrtf(red[0] * (1.0f / 128.0f) + 1e-5f);
    zs[m] = dv * rstd * nw[m] + nb[m];
    __syncthreads();
    if (m < NC_) {
        float acc = cb[m];
#pragma unroll 8
        for (int k = 0; k < 128; ++k) acc = fmaf(zs[k], cw[k * 10 + m], acc);
        out[b * 10 + m] = acc;
    }
}

extern "C" void kernel_launch(void* const* d_in, const int* in_sizes, int n_in,
                              void* d_out, int out_size, void* d_ws, size_t ws_size,
                              hipStream_t stream) {
    const float* x    = (const float*)d_in[0];
    const float* Win  = (const float*)d_in[1];
    const float* bin  = (const float*)d_in[2];
    const float* lnw  = (const float*)d_in[3];
    const float* lnb  = (const float*)d_in[4];
    const float* ipw  = (const float*)d_in[5];
    const float* cw   = (const float*)d_in[6];
    const float* cb   = (const float*)d_in[7];
    const float* xpw  = (const float*)d_in[8];
    const float* dtw  = (const float*)d_in[9];
    const float* dtb  = (const float*)d_in[10];
    const float* Alog = (const float*)d_in[11];
    const float* Dp   = (const float*)d_in[12];
    const float* opw  = (const float*)d_in[13];
    const float* opb  = (const float*)d_in[14];
    const float* nw   = (const float*)d_in[15];
    const float* nb   = (const float*)d_in[16];
    const float* clw  = (const float*)d_in[17];
    const float* clb  = (const float*)d_in[18];

    // f32-slot offsets (all non-overlapping):
    //   h        [0,        4194304)
    //   P        [4194304,  6291456)   (zb bf16 aliases P; dead before P used)
    //   Sb       [6291456,  8388608)
    //   xzb bf16 [8388608,  16777216)
    //   xcb bf16 [16777216, 20971520)
    //   projall  [20971520, 25690112)
    //   yb bf16  [25690112, 29884416)
    //   partial  [29884416, 29917184)
    //   wt1      [29917184, 30048256)
    //   wt2      [30048256, 30113792)
    //   wcat     [30113792, 30310400)
    float* ws = (float*)d_ws;
    float*  h       = ws;
    float*  P       = ws + 4194304;
    float*  Sb      = ws + 6291456;
    __bf16* zb      = (__bf16*)P;
    __bf16* xzb     = (__bf16*)(ws + 8388608);
    __bf16* xcb     = (__bf16*)(ws + 16777216);
    __bf16* projall = (__bf16*)(ws + 20971520);
    __bf16* yb      = (__bf16*)(ws + 25690112);
    float*  partial = ws + 29884416;
    __bf16* wt1     = (__bf16*)(ws + 29917184);
    __bf16* wt2     = (__bf16*)(ws + 30048256);
    __bf16* wcat    = (__bf16*)(ws + 30113792);

    k_prep_w<<<1024, 256, 0, stream>>>(ipw, opw, wt1, wt2);
    k_prep_wcat<<<4 * 384, 256, 0, stream>>>(xpw, dtw, wcat);
    k_embed<<<T_, 128, 0, stream>>>(x, Win, bin, h);
    for (int lay = 0; lay < 4; ++lay) {
        k_ln<<<T_ / 4, 256, 0, stream>>>(h, lnw + lay * 128, lnb + lay * 128, zb);
        k_gemm_mfma<64, 128, 512, 0, false><<<dim3(T_ / 64, 4), 256, 0, stream>>>(
            zb, nullptr, wt1 + (size_t)lay * 65536, nullptr, nullptr, xzb);
        k_conv<<<T_ / 4, 256, 0, stream>>>(xzb, cw + lay * 1024, cb + lay * 256, xcb);
        k_gemm_mfma<64, 256, 384, 1, false><<<dim3(T_ / 64, 3), 256, 0, stream>>>(
            xcb, nullptr, wcat + (size_t)lay * 98304, dtb + lay * 256, nullptr, projall);
        k_scan_chunk<false><<<dim3(2, NCH_, B_), 128, 0, stream>>>(projall, xcb,
            Alog + lay * 4096, Dp + lay * 256, P, Sb, yb);
        k_scan_combine<<<B_ * 4096 / 256, 256, 0, stream>>>(P, Sb);
        k_scan_chunk<true><<<dim3(2, NCH_, B_), 128, 0, stream>>>(projall, xcb,
            Alog + lay * 4096, Dp + lay * 256, P, Sb, yb);
        k_gemm_mfma<32, 256, 128, 2, true><<<dim3(T_ / 32, 1), 256, 0, stream>>>(
            yb, xzb, wt2 + (size_t)lay * 32768, opb + lay * 128, h, nullptr);
    }
    k_pool<<<dim3(32, 8), 128, 0, stream>>>(h, partial);
    k_head<<<32, 128, 0, stream>>>(partial, nw, nb, clw, clb, (float*)d_out);
}